// Round 7
// baseline (4205.730 us; speedup 1.0000x reference)
//
#include <hip/hip_runtime.h>

#define AS1 __attribute__((address_space(1)))
#define AS3 __attribute__((address_space(3)))

typedef __attribute__((ext_vector_type(8))) _Float16 f16x8;
typedef __attribute__((ext_vector_type(4))) float f32x4;

static constexpr int BATCH = 4096;
static constexpr int SEQ   = 15;

__device__ __forceinline__ float h2f(unsigned short u) {
  return (float)__builtin_bit_cast(_Float16, u);
}
__device__ __forceinline__ unsigned short f2h(float f) {
  return __builtin_bit_cast(unsigned short, (_Float16)f);   // RNE
}
__device__ __forceinline__ float frcp(float x) { return __builtin_amdgcn_rcpf(x); }
__device__ __forceinline__ float sigm(float x)  { return frcp(1.0f + __expf(-x)); }
__device__ __forceinline__ float tanhx(float x) { return 1.0f - 2.0f * frcp(1.0f + __expf(2.0f * x)); }

// ---------------------------------------------------------------------------
// 8-phase 256x256 GEMM with fused LSTM epilogue (T2+T3+T4+T5).
// C(M=4096, N=4096) = A(M,K) fp16 @ B(N,K)^T fp16, K%64==0, A split at K0.
// 512 thr = 8 waves (2M x 4N); BK=64; LDS 128KB dbuf; st_16x32 swizzle;
// counted vmcnt(4); raw s_barrier; setprio around MFMA.
// Weights gate-interleaved: gate = col&3, unit = col>>2 (see cat_w_int).
// ---------------------------------------------------------------------------
template<int STAGE>
__global__ __launch_bounds__(512, 2)
void gemm_lstm256(const unsigned short* A0, int lda0, int K0,
                  const unsigned short* A1, int lda1,
                  const unsigned short* Bw, int K,
                  const float* ib, float* Cst,
                  unsigned short* P0, unsigned short* P1, unsigned short* P2,
                  float* F0)
{
  __shared__ unsigned short lds[2][2][16384];   // [buf][A/B][256 rows x 64 cols]
  const int tid  = threadIdx.x;
  const int wid  = tid >> 6;
  const int lane = tid & 63;
  const int wr = wid >> 2;          // 0..1 (M)
  const int wc = wid & 3;           // 0..3 (N)
  const int NT = K >> 6;

  // XCD swizzle (grid 16x16 = 256 blocks, %8==0)
  const int bid = blockIdx.y * gridDim.x + blockIdx.x;
  const int cpx = (gridDim.x * gridDim.y) >> 3;
  const int swz = (bid & 7) * cpx + (bid >> 3);
  const int row0 = (swz / gridDim.x) * 256;
  const int col0 = (swz % gridDim.x) * 256;

  // stage one half-tile (128 rows x 64 cols): linear LDS dest, pre-swizzled src
  auto stage_half = [&](int bb, int mat, int hh, int kt) {
    const int k0 = kt * 64;
    const unsigned short* Ap; int lda, kc, rb;
    if (mat == 0) {
      if (k0 < K0) { Ap = A0; lda = lda0; kc = k0; }
      else         { Ap = A1; lda = lda1; kc = k0 - K0; }
      rb = row0;
    } else { Ap = Bw; lda = K; kc = k0; rb = col0; }
#pragma unroll
    for (int i = 0; i < 2; ++i) {
      const int x  = (tid + i * 512) * 16;             // LDS byte in 16KB half
      const int xs = x ^ (((x >> 9) & 1) << 5);        // logical byte (st_16x32)
      const int r  = hh * 128 + (xs >> 7);
      const int cb = xs & 127;
      const unsigned short* src = Ap + (size_t)(rb + r) * lda + kc + (cb >> 1);
      __builtin_amdgcn_global_load_lds((const AS1 void*)src,
          (AS3 void*)((char*)&lds[bb][mat][0] + hh * 16384 + wid * 1024 + i * 8192),
          16, 0, 0);
    }
  };

  // fragment read bases; swizzle XOR folds to a lane constant:
  // byte = row*128 + kk*64 + (lane>>4)*16 ; bit9 = frow&4 -> XOR bit5
  const int frow = lane & 15;
  const int axor = ((lane >> 2) & 1) << 5;
  const int abase = ((((wr * 128 + frow) << 7) + (((lane >> 4) & 3) << 4))) ^ axor;
  const int bbase = ((((wc * 64  + frow) << 7) + (((lane >> 4) & 3) << 4))) ^ axor;

  const f32x4 zero = {0.f, 0.f, 0.f, 0.f};
  f32x4 acc[8][4];
#pragma unroll
  for (int i = 0; i < 8; ++i)
#pragma unroll
    for (int j = 0; j < 4; ++j) acc[i][j] = zero;

  // prologue: tile0 (A0,A1,B0,B1) + B halves of tile1 ; drain to tile0
  stage_half(0, 0, 0, 0);
  stage_half(0, 0, 1, 0);
  stage_half(0, 1, 0, 0);
  stage_half(0, 1, 1, 0);
  if (NT > 1) { stage_half(1, 1, 0, 1); stage_half(1, 1, 1, 1); }
  asm volatile("s_waitcnt vmcnt(4)" ::: "memory");
  __builtin_amdgcn_s_barrier();

#define DO_PHASE(MB, STG, VMW)                                                        \
  {                                                                                   \
    const f16x8 a0 = *(const f16x8*)(ldsA + abase + (MB)     * 2048);                 \
    const f16x8 a1 = *(const f16x8*)(ldsA + abase + (MB)     * 2048 + 64);            \
    const f16x8 a2 = *(const f16x8*)(ldsA + abase + (MB + 1) * 2048);                 \
    const f16x8 a3 = *(const f16x8*)(ldsA + abase + (MB + 1) * 2048 + 64);            \
    STG;                                                                              \
    __builtin_amdgcn_s_barrier();                                                     \
    asm volatile("s_waitcnt lgkmcnt(0)" ::: "memory");                                \
    __builtin_amdgcn_sched_barrier(0);                                                \
    __builtin_amdgcn_s_setprio(1);                                                    \
    _Pragma("unroll")                                                                 \
    for (int n = 0; n < 4; ++n) {                                                     \
      acc[MB][n]     = __builtin_amdgcn_mfma_f32_16x16x32_f16(a0, bv[n][0], acc[MB][n],     0, 0, 0); \
      acc[MB][n]     = __builtin_amdgcn_mfma_f32_16x16x32_f16(a1, bv[n][1], acc[MB][n],     0, 0, 0); \
      acc[MB + 1][n] = __builtin_amdgcn_mfma_f32_16x16x32_f16(a2, bv[n][0], acc[MB + 1][n], 0, 0, 0); \
      acc[MB + 1][n] = __builtin_amdgcn_mfma_f32_16x16x32_f16(a3, bv[n][1], acc[MB + 1][n], 0, 0, 0); \
    }                                                                                 \
    __builtin_amdgcn_s_setprio(0);                                                    \
    VMW;                                                                              \
    __builtin_amdgcn_s_barrier();                                                     \
  }

  for (int kt = 0; kt < NT; ++kt) {
    const int cur = kt & 1;
    const char* ldsA = (const char*)&lds[cur][0][0];
    const char* ldsB = (const char*)&lds[cur][1][0];
    f16x8 bv[4][2];
#pragma unroll
    for (int n = 0; n < 4; ++n) {              // whole B strip once per tile
      bv[n][0] = *(const f16x8*)(ldsB + bbase + n * 2048);
      bv[n][1] = *(const f16x8*)(ldsB + bbase + n * 2048 + 64);
    }
    DO_PHASE(0, { if (kt + 1 < NT) stage_half(cur ^ 1, 0, 0, kt + 1); }, { (void)0; });
    DO_PHASE(2, { if (kt + 1 < NT) stage_half(cur ^ 1, 0, 1, kt + 1); }, { (void)0; });
    DO_PHASE(4, { if (kt + 2 < NT) stage_half(cur,     1, 0, kt + 2); }, { (void)0; });
    DO_PHASE(6, { if (kt + 2 < NT) stage_half(cur,     1, 1, kt + 2); },
             { if (kt >= NT - 2) { asm volatile("s_waitcnt vmcnt(0)" ::: "memory"); }
               else              { asm volatile("s_waitcnt vmcnt(4)" ::: "memory"); } });
  }
#undef DO_PHASE

  // ---- fused LSTM epilogue (all LDS free after final barrier) ----
  float* xw = ((float*)&lds[0][0][0]) + wid * 256;
  const int cs = lane & 3;
  const int er = (lane >> 4) << 2;
  const int uq = (lane >> 2) & 3;

  float cold[8][4];
#pragma unroll
  for (int mi = 0; mi < 8; ++mi)
#pragma unroll
    for (int ni = 0; ni < 4; ++ni) {
      const int R = row0 + wr * 128 + mi * 16 + er + cs;
      const int U = ((col0 + wc * 64 + ni * 16) >> 2) + uq;
      cold[mi][ni] = Cst[(size_t)R * 1024 + U];
    }

#pragma unroll
  for (int mi = 0; mi < 8; ++mi)
#pragma unroll
    for (int ni = 0; ni < 4; ++ni) {
      __builtin_amdgcn_wave_barrier();
      *(f32x4*)(xw + lane * 4) = acc[mi][ni];
      __builtin_amdgcn_wave_barrier();
      __builtin_amdgcn_sched_barrier(0);
      const int qb = (lane & 60) * 4;
      const float g0 = xw[qb + 0  + cs];
      const float g1 = xw[qb + 4  + cs];
      const float g2 = xw[qb + 8  + cs];
      const float g3 = xw[qb + 12 + cs];
      __builtin_amdgcn_wave_barrier();
      const int R = row0 + wr * 128 + mi * 16 + er + cs;
      const int U = ((col0 + wc * 64 + ni * 16) >> 2) + uq;
      const f32x4 b4 = *(const f32x4*)(ib + 4 * U);
      const float gi = g0 + b4[0];
      const float gf = g1 + b4[1];
      const float gg = g2 + b4[2];
      const float go = g3 + b4[3];
      const size_t off = (size_t)R * 1024 + U;
      const float cn = sigm(gf) * cold[mi][ni] + sigm(gi) * tanhx(gg);
      const float hn = sigm(go) * tanhx(cn);
      Cst[off] = cn;
      const unsigned short hb = f2h(hn);
      if (STAGE == 1) {
        P0[(size_t)R * 2048 + U]        = hb;        // hc: h
        P0[(size_t)R * 2048 + 1024 + U] = f2h(cn);   // hc: c
        P1[(size_t)R * 2048 + 1024 + U] = hb;        // gA_next: h half
        P2[off] = hb;                                // mid(t)
      } else {
        F0[off] = hn;                                // h2 f32
        P0[off] = hb;                                // h2b_next
      }
    }
}

// ---------------------------------------------------------------------------
// 8-phase 256x128 score GEMM, fused epilogue:
// gA[row,col] = f2h( x[row,col] * tanh(acc + b_sa[col]) ).
// A(M,K=3072) split at K0=2048 ([h|c] from hc, then x); B = W_sa (1024,3072).
// 512 thr = 8 waves (2M x 4N), wave tile 128x32; LDS 96KB dbuf; vmcnt(2).
// ---------------------------------------------------------------------------
__global__ __launch_bounds__(512, 2)
void gemm_score256(const unsigned short* A0, int lda0, int K0,
                   const unsigned short* A1, int lda1,
                   const unsigned short* Bw, int K,
                   const float* bias, const unsigned short* X,
                   unsigned short* OutG)
{
  __shared__ unsigned short lds[2][24576];      // [buf][A:16384 | B:8192]
  const int tid  = threadIdx.x;
  const int wid  = tid >> 6;
  const int lane = tid & 63;
  const int wr = wid >> 2;          // 0..1 (M)
  const int wc = wid & 3;           // 0..3 (N)
  const int NT = K >> 6;

  // XCD swizzle (grid 8x16 = 128 blocks, %8==0)
  const int bid = blockIdx.y * gridDim.x + blockIdx.x;
  const int cpx = (gridDim.x * gridDim.y) >> 3;
  const int swz = (bid & 7) * cpx + (bid >> 3);
  const int row0 = (swz / gridDim.x) * 256;
  const int col0 = (swz % gridDim.x) * 128;

  auto stage_half = [&](int bb, int mat, int hh, int kt) {
    const int k0 = kt * 64;
    if (mat == 0) {                              // A half: 128 rows, 2 issues
      const unsigned short* Ap; int lda, kc;
      if (k0 < K0) { Ap = A0; lda = lda0; kc = k0; }
      else         { Ap = A1; lda = lda1; kc = k0 - K0; }
#pragma unroll
      for (int i = 0; i < 2; ++i) {
        const int x  = (tid + i * 512) * 16;
        const int xs = x ^ (((x >> 9) & 1) << 5);
        const int r  = hh * 128 + (xs >> 7);
        const int cb = xs & 127;
        const unsigned short* src = Ap + (size_t)(row0 + r) * lda + kc + (cb >> 1);
        __builtin_amdgcn_global_load_lds((const AS1 void*)src,
            (AS3 void*)((char*)&lds[bb][0] + hh * 16384 + wid * 1024 + i * 8192),
            16, 0, 0);
      }
    } else {                                     // B half: 64 rows, 1 issue
      const int x  = tid * 16;
      const int xs = x ^ (((x >> 9) & 1) << 5);
      const int r  = hh * 64 + (xs >> 7);
      const int cb = xs & 127;
      const unsigned short* src = Bw + (size_t)(col0 + r) * K + k0 + (cb >> 1);
      __builtin_amdgcn_global_load_lds((const AS1 void*)src,
          (AS3 void*)((char*)&lds[bb][0] + 32768 + hh * 8192 + wid * 1024),
          16, 0, 0);
    }
  };

  const int frow = lane & 15;
  const int axor = ((lane >> 2) & 1) << 5;
  const int abase = ((((wr * 128 + frow) << 7) + (((lane >> 4) & 3) << 4))) ^ axor;
  const int bbase = ((((wc * 32  + frow) << 7) + (((lane >> 4) & 3) << 4))) ^ axor;

  const f32x4 zero = {0.f, 0.f, 0.f, 0.f};
  f32x4 acc[8][2];
#pragma unroll
  for (int i = 0; i < 8; ++i)
#pragma unroll
    for (int j = 0; j < 2; ++j) acc[i][j] = zero;

  // prologue: tile0 (A0,A1,B0,B1) + B halves of tile1 ; drain tile0
  stage_half(0, 0, 0, 0);
  stage_half(0, 0, 1, 0);
  stage_half(0, 1, 0, 0);
  stage_half(0, 1, 1, 0);
  if (NT > 1) { stage_half(1, 1, 0, 1); stage_half(1, 1, 1, 1); }
  asm volatile("s_waitcnt vmcnt(2)" ::: "memory");
  __builtin_amdgcn_s_barrier();

#define DO_PHASE_S(MB, STG, VMW)                                                      \
  {                                                                                   \
    const f16x8 a0 = *(const f16x8*)(ldsA + abase + (MB)     * 2048);                 \
    const f16x8 a1 = *(const f16x8*)(ldsA + abase + (MB)     * 2048 + 64);            \
    const f16x8 a2 = *(const f16x8*)(ldsA + abase + (MB + 1) * 2048);                 \
    const f16x8 a3 = *(const f16x8*)(ldsA + abase + (MB + 1) * 2048 + 64);            \
    STG;                                                                              \
    __builtin_amdgcn_s_barrier();                                                     \
    asm volatile("s_waitcnt lgkmcnt(0)" ::: "memory");                                \
    __builtin_amdgcn_sched_barrier(0);                                                \
    __builtin_amdgcn_s_setprio(1);                                                    \
    _Pragma("unroll")                                                                 \
    for (int n = 0; n < 2; ++n) {                                                     \
      acc[MB][n]     = __builtin_amdgcn_mfma_f32_16x16x32_f16(a0, bv[n][0], acc[MB][n],     0, 0, 0); \
      acc[MB][n]     = __builtin_amdgcn_mfma_f32_16x16x32_f16(a1, bv[n][1], acc[MB][n],     0, 0, 0); \
      acc[MB + 1][n] = __builtin_amdgcn_mfma_f32_16x16x32_f16(a2, bv[n][0], acc[MB + 1][n], 0, 0, 0); \
      acc[MB + 1][n] = __builtin_amdgcn_mfma_f32_16x16x32_f16(a3, bv[n][1], acc[MB + 1][n], 0, 0, 0); \
    }                                                                                 \
    __builtin_amdgcn_s_setprio(0);                                                    \
    VMW;                                                                              \
    __builtin_amdgcn_s_barrier();                                                     \
  }

  for (int kt = 0; kt < NT; ++kt) {
    const int cur = kt & 1;
    const char* ldsA = (const char*)&lds[cur][0];
    const char* ldsB = ldsA + 32768;
    f16x8 bv[2][2];
#pragma unroll
    for (int n = 0; n < 2; ++n) {
      bv[n][0] = *(const f16x8*)(ldsB + bbase + n * 2048);
      bv[n][1] = *(const f16x8*)(ldsB + bbase + n * 2048 + 64);
    }
    DO_PHASE_S(0, { if (kt + 1 < NT) stage_half(cur ^ 1, 0, 0, kt + 1); }, { (void)0; });
    DO_PHASE_S(2, { if (kt + 1 < NT) stage_half(cur ^ 1, 0, 1, kt + 1); }, { (void)0; });
    DO_PHASE_S(4, { if (kt + 2 < NT) stage_half(cur,     1, 0, kt + 2); }, { (void)0; });
    DO_PHASE_S(6, { if (kt + 2 < NT) stage_half(cur,     1, 1, kt + 2); },
             { if (kt >= NT - 2) { asm volatile("s_waitcnt vmcnt(0)" ::: "memory"); }
               else              { asm volatile("s_waitcnt vmcnt(2)" ::: "memory"); } });
  }
#undef DO_PHASE_S

  // ---- fused score epilogue ----
  const int er = (lane >> 4) << 2;
#pragma unroll
  for (int mi = 0; mi < 8; ++mi)
#pragma unroll
    for (int ni = 0; ni < 2; ++ni) {
      const int row = row0 + wr * 128 + mi * 16 + er;
      const int col = col0 + wc * 32 + ni * 16 + frow;
      const float bs = bias[col];
#pragma unroll
      for (int r = 0; r < 4; ++r) {
        const float v = tanhx(acc[mi][ni][r] + bs);
        const float xv = h2f(X[(size_t)(row + r) * 1024 + col]);
        OutG[(size_t)(row + r) * 2048 + col] = f2h(xv * v);
      }
    }
}

// ---------------------------------------------------------------------------
// Prep kernels
// ---------------------------------------------------------------------------
__global__ void f2h_copy(const float* src, unsigned short* dst, int n) {
  const int i = blockIdx.x * 256 + threadIdx.x;
  if (i < n) dst[i] = f2h(src[i]);
}

// dst (4096,2048) gate-interleaved: dst[4u+g] = [Wih[g*1024+u] | Whh[g*1024+u]]
__global__ void cat_w_int(const float* wih, const float* whh, unsigned short* dst) {
  const int i = blockIdx.x * 256 + threadIdx.x;   // 4096*2048
  const int n = i >> 11, k = i & 2047;
  const int u = n >> 2, g = n & 3;
  const int src = g * 1024 + u;
  dst[i] = f2h(k < 1024 ? wih[src * 1024 + k] : whh[src * 1024 + (k - 1024)]);
}

// interleaved bias: ib[4u+g] = bih[g*1024+u] + bhh[g*1024+u]
__global__ void prep_bias(const float* bih, const float* bhh, float* ib) {
  const int i = blockIdx.x * 256 + threadIdx.x;   // 4096
  const int u = i >> 2, g = i & 3;
  ib[i] = bih[g * 1024 + u] + bhh[g * 1024 + u];
}

// vectorized p_q copy with (b,s,.) -> (t,b,.) transpose
__global__ void copy_pq(const float* pq, unsigned short* inb) {
  const int i4 = blockIdx.x * 256 + threadIdx.x;  // float4 index
  const float4 v = ((const float4*)pq)[i4];
  const int base = i4 * 4;
  const float vv[4] = {v.x, v.y, v.z, v.w};
#pragma unroll
  for (int e = 0; e < 4; ++e) {
    const int idx = base + e;
    const int bt = idx / 1003;
    const int j = idx - bt * 1003;
    const int b = bt / 15;
    const int t = bt - b * 15;
    inb[((size_t)t * BATCH + b) * 1024 + j] = f2h(vv[e]);
  }
}

// cfg linear (10 outputs, K=128) + 11 embedding cols; one wave per (b,t) row
__global__ void cfg_emb(const float* cfg, const int* tim,
                        const float* Wc, const float* bc,
                        const float* eh, const float* ew, const float* es,
                        unsigned short* inb)
{
  const int wv = (blockIdx.x * 256 + threadIdx.x) >> 6;  // row = b*15+t
  const int lane = threadIdx.x & 63;
  const int b = wv / 15, t = wv - b * 15;
  const float* cp = cfg + (size_t)wv * 128;
  const float c0 = cp[lane], c1v = cp[lane + 64];
  unsigned short* dst = inb + ((size_t)t * BATCH + b) * 1024;
#pragma unroll
  for (int g = 0; g < 10; ++g) {
    float v = fmaf(c0, Wc[g * 128 + lane], c1v * Wc[g * 128 + 64 + lane]);
    v += __shfl_xor(v, 32); v += __shfl_xor(v, 16); v += __shfl_xor(v, 8);
    v += __shfl_xor(v, 4);  v += __shfl_xor(v, 2);  v += __shfl_xor(v, 1);
    if (lane == 0) dst[1003 + g] = f2h(v + bc[g]);
  }
  if (lane < 5)       dst[1013 + lane] = f2h(eh[tim[wv * 3 + 0] * 5 + lane]);
  else if (lane < 8)  dst[1018 + (lane - 5)] = f2h(ew[tim[wv * 3 + 1] * 3 + (lane - 5)]);
  else if (lane < 11) dst[1021 + (lane - 8)] = f2h(es[tim[wv * 3 + 2] * 3 + (lane - 8)]);
}

// ---------------------------------------------------------------------------
// BatchNorm over (B,H) per s
// ---------------------------------------------------------------------------
__global__ void bn_partial(const unsigned short* mid, float* part) {
  const int t = blockIdx.y, blk = blockIdx.x, tid = threadIdx.x;
  const unsigned short* p = mid + (size_t)t * BATCH * 1024;
  float s = 0.f, ss = 0.f;
  for (int i = blk * 256 + tid; i < BATCH * 1024; i += 128 * 256) {
    const float v = h2f(p[i]);
    s += v; ss += v * v;
  }
  for (int o = 32; o > 0; o >>= 1) { s += __shfl_down(s, o); ss += __shfl_down(ss, o); }
  __shared__ float sm[8];
  if ((tid & 63) == 0) { sm[(tid >> 6) * 2] = s; sm[(tid >> 6) * 2 + 1] = ss; }
  __syncthreads();
  if (tid == 0) {
    part[(t * 128 + blk) * 2]     = sm[0] + sm[2] + sm[4] + sm[6];
    part[(t * 128 + blk) * 2 + 1] = sm[1] + sm[3] + sm[5] + sm[7];
  }
}

__global__ void bn_final(const float* part, const float* gamma, const float* beta, float* scsh) {
  const int t = blockIdx.x, tid = threadIdx.x;  // 128 threads
  float s = part[(t * 128 + tid) * 2], ss = part[(t * 128 + tid) * 2 + 1];
  for (int o = 32; o > 0; o >>= 1) { s += __shfl_down(s, o); ss += __shfl_down(ss, o); }
  __shared__ float sm[4];
  if ((tid & 63) == 0) { sm[(tid >> 6) * 2] = s; sm[(tid >> 6) * 2 + 1] = ss; }
  __syncthreads();
  if (tid == 0) {
    const float S = sm[0] + sm[2], SS = sm[1] + sm[3];
    const float inv = 1.f / (float)(BATCH * 1024);
    const float mu = S * inv;
    const float var = SS * inv - mu * mu;
    const float rstd = rsqrtf(var + 1e-5f);
    const float sc = rstd * gamma[t];
    scsh[t * 2] = sc;
    scsh[t * 2 + 1] = beta[t] - mu * sc;
  }
}

__global__ void bn_apply(unsigned short* mid, const float* scsh) {
  const int t = blockIdx.y;
  const int i = blockIdx.x * 256 + threadIdx.x;
  unsigned short* p = mid + (size_t)t * BATCH * 1024;
  p[i] = f2h(h2f(p[i]) * scsh[t * 2] + scsh[t * 2 + 1]);
}

// ---------------------------------------------------------------------------
// Stage-2 attention/proj
// ---------------------------------------------------------------------------
__global__ void att_proj(const float* h2, const float* c2, const unsigned short* xn,
                         const float* Wta, const float* bta, const float* Wihd,
                         float* att2, float* proj, int t)
{
  const int b = blockIdx.x, tid = threadIdx.x;   // 256 threads
  const float* h = h2 + (size_t)b * 1024;
  const float* c = c2 + (size_t)b * 1024;
  const unsigned short* x = xn + (size_t)b * 1024;
  float a = 0.f, p0 = 0.f, p1 = 0.f, p2 = 0.f, p3 = 0.f;
  for (int j = tid; j < 1024; j += 256) {
    const float hv = h[j], cv = c[j], xv = h2f(x[j]);
    a  += hv * Wta[j] + cv * Wta[1024 + j] + xv * Wta[2048 + j];
    p0 += hv * Wihd[j];
    p1 += hv * Wihd[1024 + j];
    p2 += hv * Wihd[2048 + j];
    p3 += hv * Wihd[3072 + j];
  }
  for (int o = 32; o > 0; o >>= 1) {
    a  += __shfl_down(a, o);  p0 += __shfl_down(p0, o); p1 += __shfl_down(p1, o);
    p2 += __shfl_down(p2, o); p3 += __shfl_down(p3, o);
  }
  __shared__ float sm[4][5];
  if ((tid & 63) == 0) {
    const int w = tid >> 6;
    sm[w][0] = a; sm[w][1] = p0; sm[w][2] = p1; sm[w][3] = p2; sm[w][4] = p3;
  }
  __syncthreads();
  if (tid == 0) {
    att2[b * SEQ + t] = tanhx(sm[0][0] + sm[1][0] + sm[2][0] + sm[3][0] + bta[0]);
    float* pp = proj + ((size_t)b * SEQ + t) * 4;
    pp[0] = sm[0][1] + sm[1][1] + sm[2][1] + sm[3][1];
    pp[1] = sm[0][2] + sm[1][2] + sm[2][2] + sm[3][2];
    pp[2] = sm[0][3] + sm[1][3] + sm[2][3] + sm[3][3];
    pp[3] = sm[0][4] + sm[1][4] + sm[2][4] + sm[3][4];
  }
}

// ---------------------------------------------------------------------------
// Stage 3: chunked pipelined-Jacobi scalar LSTM (exact after 8 iters)
// ---------------------------------------------------------------------------
__global__ __launch_bounds__(256) void lstm3_par(
    const float* proj, const float* Whhd,
    const float* bihd, const float* bhhd, float* out1d)
{
  const int s = blockIdx.x;            // 0..14
  const int tid = threadIdx.x;         // 0..255
  constexpr int CH = BATCH / 256;      // 16
  const float wi = Whhd[0], wf = Whhd[1], wg = Whhd[2], wo = Whhd[3];
  const float bi = bihd[0] + bhhd[0], bf_ = bihd[1] + bhhd[1];
  const float bg = bihd[2] + bhhd[2], bo = bihd[3] + bhhd[3];
  const float4* p4 = (const float4*)proj;
  float4 p[CH];
#pragma unroll
  for (int u = 0; u < CH; ++u) p[u] = p4[(tid * CH + u) * SEQ + s];
  __shared__ float Hb[257], Cb[257];
  Hb[tid] = 0.f; Cb[tid] = 0.f;
  if (tid == 255) { Hb[256] = 0.f; Cb[256] = 0.f; }
  __syncthreads();
  float h, c;
  for (int it = 0; it < 8; ++it) {
    h = Hb[tid]; c = Cb[tid];
#pragma unroll
    for (int u = 0; u < CH; ++u) {
      const float gi = fmaf(h, wi, p[u].x + bi);
      const float gf = fmaf(h, wf, p[u].y + bf_);
      const float gg = fmaf(h, wg, p[u].z + bg);
      const float go = fmaf(h, wo, p[u].w + bo);
      c = sigm(gf) * c + sigm(gi) * tanhx(gg);
      h = sigm(go) * tanhx(c);
    }
    __syncthreads();
    Hb[tid + 1] = h; Cb[tid + 1] = c;
    __syncthreads();
  }
  h = Hb[tid]; c = Cb[tid];
#pragma unroll
  for (int u = 0; u < CH; ++u) {
    const float gi = fmaf(h, wi, p[u].x + bi);
    const float gf = fmaf(h, wf, p[u].y + bf_);
    const float gg = fmaf(h, wg, p[u].z + bg);
    const float go = fmaf(h, wo, p[u].w + bo);
    c = sigm(gf) * c + sigm(gi) * tanhx(gg);
    h = sigm(go) * tanhx(c);
    out1d[(tid * CH + u) * SEQ + s] = h;
  }
}

__global__ void finalize_k(const float* att2, const float* out1d, float* out) {
  const int b = blockIdx.x * 64 + threadIdx.x;
  const float* a = att2 + b * SEQ;
  const float* o = out1d + b * SEQ;
  float m = -1e30f;
  for (int s = 0; s < SEQ; ++s) m = fmaxf(m, a[s]);
  float den = 0.f, num = 0.f;
  for (int s = 0; s < SEQ; ++s) {
    const float e = __expf(a[s] - m);
    den += e; num += e * o[s];
  }
  out[b] = num / den;
}

// ---------------------------------------------------------------------------
extern "C" void kernel_launch(void* const* d_in, const int* in_sizes, int n_in,
                              void* d_out, int out_size, void* d_ws, size_t ws_size,
                              hipStream_t stream)
{
  (void)in_sizes; (void)n_in; (void)out_size; (void)ws_size;
  const float* in_pq   = (const float*)d_in[0];
  const float* in_cfg  = (const float*)d_in[1];
  const int*   in_time = (const int*)d_in[2];
  const float* W_cfg   = (const float*)d_in[3];
  const float* b_cfg   = (const float*)d_in[4];
  const float* emb_h   = (const float*)d_in[5];
  const float* emb_w   = (const float*)d_in[6];
  const float* emb_s   = (const float*)d_in[7];
  const float* W_sa    = (const float*)d_in[8];
  const float* b_sa    = (const float*)d_in[9];
  const float* Wih_s   = (const float*)d_in[10];
  const float* Whh_s   = (const float*)d_in[11];
  const float* bih_s   = (const float*)d_in[12];
  const float* bhh_s   = (const float*)d_in[13];
  const float* Wih_t   = (const float*)d_in[14];
  const float* Whh_t   = (const float*)d_in[15];
  const float* bih_t   = (const float*)d_in[16];
  const float* bhh_t   = (const float*)d_in[17];
  const float* W_ta    = (const float*)d_in[18];
  const float* b_ta    = (const float*)d_in[19];
  const float* gamma   = (const float*)d_in[20];
  const float* beta    = (const float*)d_in[21];
  const float* Wih_d   = (const float*)d_in[22];
  const float* Whh_d   = (const float*)d_in[23];
  const float* bih_d   = (const float*)d_in[24];
  const float* bhh_d   = (const float*)d_in[25];
  float* out = (float*)d_out;

  char* w = (char*)d_ws;
  size_t off = 0;
  auto alloc = [&](size_t bytes) -> char* {
    char* p = w + off;
    off = (off + bytes + 255) & ~(size_t)255;
    return p;
  };
  unsigned short* inb  = (unsigned short*)alloc((size_t)SEQ * BATCH * 1024 * 2); // x -> mid -> mid_norm
  unsigned short* hc   = (unsigned short*)alloc((size_t)BATCH * 2048 * 2);       // [h|c] fp16 (stage1)
  unsigned short* gA0  = (unsigned short*)alloc((size_t)BATCH * 2048 * 2);       // [xs|h] ping
  unsigned short* gA1  = (unsigned short*)alloc((size_t)BATCH * 2048 * 2);       // [xs|h] pong
  float*          c1   = (float*)alloc((size_t)BATCH * 1024 * 4);
  unsigned short* h2b0 = (unsigned short*)alloc((size_t)BATCH * 1024 * 2);
  unsigned short* h2b1 = (unsigned short*)alloc((size_t)BATCH * 1024 * 2);
  float*          h2f_ = (float*)alloc((size_t)BATCH * 1024 * 4);
  float*          c2f  = (float*)alloc((size_t)BATCH * 1024 * 4);
  unsigned short* wsab = (unsigned short*)alloc((size_t)1024 * 3072 * 2);
  unsigned short* w1   = (unsigned short*)alloc((size_t)4096 * 2048 * 2);
  unsigned short* w2   = (unsigned short*)alloc((size_t)4096 * 2048 * 2);
  float*          ib1  = (float*)alloc(4096 * 4);
  float*          ib2  = (float*)alloc(4096 * 4);
  float*          part = (float*)alloc(15 * 128 * 2 * 4);
  float*          scsh = (float*)alloc(15 * 2 * 4);
  float*          att2 = (float*)alloc((size_t)BATCH * SEQ * 4);
  float*          proj = (float*)alloc((size_t)BATCH * SEQ * 4 * 4);
  float*          o1d  = (float*)alloc((size_t)BATCH * SEQ * 4);

  unsigned short* gAbuf[2]  = {gA0, gA1};
  unsigned short* h2bbuf[2] = {h2b0, h2b1};

  // zero recurrent state each call (deterministic)
  hipMemsetAsync(hc,   0, (size_t)BATCH * 2048 * 2, stream);
  hipMemsetAsync(gA0,  0, (size_t)BATCH * 2048 * 2, stream);
  hipMemsetAsync(c1,   0, (size_t)BATCH * 1024 * 4, stream);
  hipMemsetAsync(h2b0, 0, (size_t)BATCH * 1024 * 2, stream);
  hipMemsetAsync(c2f,  0, (size_t)BATCH * 1024 * 4, stream);

  // weight conversion + input assembly
  f2h_copy<<<(1024 * 3072) / 256, 256, 0, stream>>>(W_sa, wsab, 1024 * 3072);
  cat_w_int<<<(4096 * 2048) / 256, 256, 0, stream>>>(Wih_s, Whh_s, w1);
  cat_w_int<<<(4096 * 2048) / 256, 256, 0, stream>>>(Wih_t, Whh_t, w2);
  prep_bias<<<16, 256, 0, stream>>>(bih_s, bhh_s, ib1);
  prep_bias<<<16, 256, 0, stream>>>(bih_t, bhh_t, ib2);
  copy_pq<<<(BATCH * SEQ * 1003 / 4) / 256, 256, 0, stream>>>(in_pq, inb);
  cfg_emb<<<(BATCH * SEQ) / 4, 256, 0, stream>>>(in_cfg, in_time, W_cfg, b_cfg,
                                                 emb_h, emb_w, emb_s, inb);

  // ---- stage 1 (8-phase score GEMM + fused-LSTM 8-phase gates GEMM) ----
  for (int t = 0; t < SEQ; ++t) {
    unsigned short* xt = inb + (size_t)t * BATCH * 1024;
    gemm_score256<<<dim3(1024 / 128, BATCH / 256), 512, 0, stream>>>(
        hc, 2048, 2048, xt, 1024, wsab, 3072, b_sa, xt, gAbuf[t & 1]);
    gemm_lstm256<1><<<dim3(4096 / 256, BATCH / 256), 512, 0, stream>>>(
        gAbuf[t & 1], 2048, 2048, gAbuf[t & 1], 2048, w1, 2048,
        ib1, c1, hc, gAbuf[(t + 1) & 1], xt, nullptr);
  }

  // ---- batchnorm over (B,H) per s ----
  bn_partial<<<dim3(128, SEQ), 256, 0, stream>>>(inb, part);
  bn_final<<<SEQ, 128, 0, stream>>>(part, gamma, beta, scsh);
  bn_apply<<<dim3((BATCH * 1024) / 256, SEQ), 256, 0, stream>>>(inb, scsh);

  // ---- stage 2 (fused-LSTM 8-phase gates GEMM + attention/proj) ----
  for (int t = 0; t < SEQ; ++t) {
    const unsigned short* xt = inb + (size_t)t * BATCH * 1024;
    gemm_lstm256<2><<<dim3(4096 / 256, BATCH / 256), 512, 0, stream>>>(
        xt, 1024, 1024, h2bbuf[t & 1], 1024, w2, 2048,
        ib2, c2f, h2bbuf[(t + 1) & 1], nullptr, nullptr, h2f_);
    att_proj<<<BATCH, 256, 0, stream>>>(h2f_, c2f, xt, W_ta, b_ta, Wih_d, att2, proj, t);
  }

  // ---- stage 3 + output ----
  lstm3_par<<<SEQ, 256, 0, stream>>>(proj, Whh_d, bih_d, bhh_d, o1d);
  finalize_k<<<BATCH / 64, 64, 0, stream>>>(att2, o1d, out);
}

// Round 8
// 3543.948 us; speedup vs baseline: 1.1867x; 1.1867x over previous
//
#include <hip/hip_runtime.h>

#define AS1 __attribute__((address_space(1)))
#define AS3 __attribute__((address_space(3)))

typedef __attribute__((ext_vector_type(8))) _Float16 f16x8;
typedef __attribute__((ext_vector_type(4))) float f32x4;

static constexpr int BATCH = 4096;
static constexpr int SEQ   = 15;

__device__ __forceinline__ float h2f(unsigned short u) {
  return (float)__builtin_bit_cast(_Float16, u);
}
__device__ __forceinline__ unsigned short f2h(float f) {
  return __builtin_bit_cast(unsigned short, (_Float16)f);   // RNE
}
__device__ __forceinline__ float frcp(float x) { return __builtin_amdgcn_rcpf(x); }
__device__ __forceinline__ float sigm(float x)  { return frcp(1.0f + __expf(-x)); }
__device__ __forceinline__ float tanhx(float x) { return 1.0f - 2.0f * frcp(1.0f + __expf(2.0f * x)); }

// ---------------------------------------------------------------------------
// 8-phase 256x256 GEMM with fused LSTM epilogue (T2+T3+T4+T5).
// Epilogue stores coalesced via LDS staging (LDS free after K-loop).
// ---------------------------------------------------------------------------
template<int STAGE>
__global__ __launch_bounds__(512, 2)
void gemm_lstm256(const unsigned short* A0, int lda0, int K0,
                  const unsigned short* A1, int lda1,
                  const unsigned short* Bw, int K,
                  const float* ib, float* Cst,
                  unsigned short* P0, unsigned short* P1, unsigned short* P2,
                  float* F0)
{
  __shared__ unsigned short lds[2][2][16384];   // [buf][A/B][256 rows x 64 cols]
  const int tid  = threadIdx.x;
  const int wid  = tid >> 6;
  const int lane = tid & 63;
  const int wr = wid >> 2;          // 0..1 (M)
  const int wc = wid & 3;           // 0..3 (N)
  const int NT = K >> 6;

  // XCD swizzle (grid 16x16 = 256 blocks, %8==0)
  const int bid = blockIdx.y * gridDim.x + blockIdx.x;
  const int cpx = (gridDim.x * gridDim.y) >> 3;
  const int swz = (bid & 7) * cpx + (bid >> 3);
  const int row0 = (swz / gridDim.x) * 256;
  const int col0 = (swz % gridDim.x) * 256;

  auto stage_half = [&](int bb, int mat, int hh, int kt) {
    const int k0 = kt * 64;
    const unsigned short* Ap; int lda, kc, rb;
    if (mat == 0) {
      if (k0 < K0) { Ap = A0; lda = lda0; kc = k0; }
      else         { Ap = A1; lda = lda1; kc = k0 - K0; }
      rb = row0;
    } else { Ap = Bw; lda = K; kc = k0; rb = col0; }
#pragma unroll
    for (int i = 0; i < 2; ++i) {
      const int x  = (tid + i * 512) * 16;             // LDS byte in 16KB half
      const int xs = x ^ (((x >> 9) & 1) << 5);        // logical byte (st_16x32)
      const int r  = hh * 128 + (xs >> 7);
      const int cb = xs & 127;
      const unsigned short* src = Ap + (size_t)(rb + r) * lda + kc + (cb >> 1);
      __builtin_amdgcn_global_load_lds((const AS1 void*)src,
          (AS3 void*)((char*)&lds[bb][mat][0] + hh * 16384 + wid * 1024 + i * 8192),
          16, 0, 0);
    }
  };

  const int frow = lane & 15;
  const int axor = ((lane >> 2) & 1) << 5;
  const int abase = ((((wr * 128 + frow) << 7) + (((lane >> 4) & 3) << 4))) ^ axor;
  const int bbase = ((((wc * 64  + frow) << 7) + (((lane >> 4) & 3) << 4))) ^ axor;

  const f32x4 zero = {0.f, 0.f, 0.f, 0.f};
  f32x4 acc[8][4];
#pragma unroll
  for (int i = 0; i < 8; ++i)
#pragma unroll
    for (int j = 0; j < 4; ++j) acc[i][j] = zero;

  stage_half(0, 0, 0, 0);
  stage_half(0, 0, 1, 0);
  stage_half(0, 1, 0, 0);
  stage_half(0, 1, 1, 0);
  if (NT > 1) { stage_half(1, 1, 0, 1); stage_half(1, 1, 1, 1); }
  asm volatile("s_waitcnt vmcnt(4)" ::: "memory");
  __builtin_amdgcn_s_barrier();

#define DO_PHASE(MB, STG, VMW)                                                        \
  {                                                                                   \
    const f16x8 a0 = *(const f16x8*)(ldsA + abase + (MB)     * 2048);                 \
    const f16x8 a1 = *(const f16x8*)(ldsA + abase + (MB)     * 2048 + 64);            \
    const f16x8 a2 = *(const f16x8*)(ldsA + abase + (MB + 1) * 2048);                 \
    const f16x8 a3 = *(const f16x8*)(ldsA + abase + (MB + 1) * 2048 + 64);            \
    STG;                                                                              \
    __builtin_amdgcn_s_barrier();                                                     \
    asm volatile("s_waitcnt lgkmcnt(0)" ::: "memory");                                \
    __builtin_amdgcn_sched_barrier(0);                                                \
    __builtin_amdgcn_s_setprio(1);                                                    \
    _Pragma("unroll")                                                                 \
    for (int n = 0; n < 4; ++n) {                                                     \
      acc[MB][n]     = __builtin_amdgcn_mfma_f32_16x16x32_f16(a0, bv[n][0], acc[MB][n],     0, 0, 0); \
      acc[MB][n]     = __builtin_amdgcn_mfma_f32_16x16x32_f16(a1, bv[n][1], acc[MB][n],     0, 0, 0); \
      acc[MB + 1][n] = __builtin_amdgcn_mfma_f32_16x16x32_f16(a2, bv[n][0], acc[MB + 1][n], 0, 0, 0); \
      acc[MB + 1][n] = __builtin_amdgcn_mfma_f32_16x16x32_f16(a3, bv[n][1], acc[MB + 1][n], 0, 0, 0); \
    }                                                                                 \
    __builtin_amdgcn_s_setprio(0);                                                    \
    VMW;                                                                              \
    __builtin_amdgcn_s_barrier();                                                     \
  }

  for (int kt = 0; kt < NT; ++kt) {
    const int cur = kt & 1;
    const char* ldsA = (const char*)&lds[cur][0][0];
    const char* ldsB = (const char*)&lds[cur][1][0];
    f16x8 bv[4][2];
#pragma unroll
    for (int n = 0; n < 4; ++n) {
      bv[n][0] = *(const f16x8*)(ldsB + bbase + n * 2048);
      bv[n][1] = *(const f16x8*)(ldsB + bbase + n * 2048 + 64);
    }
    DO_PHASE(0, { if (kt + 1 < NT) stage_half(cur ^ 1, 0, 0, kt + 1); }, { (void)0; });
    DO_PHASE(2, { if (kt + 1 < NT) stage_half(cur ^ 1, 0, 1, kt + 1); }, { (void)0; });
    DO_PHASE(4, { if (kt + 2 < NT) stage_half(cur,     1, 0, kt + 2); }, { (void)0; });
    DO_PHASE(6, { if (kt + 2 < NT) stage_half(cur,     1, 1, kt + 2); },
             { if (kt >= NT - 2) { asm volatile("s_waitcnt vmcnt(0)" ::: "memory"); }
               else              { asm volatile("s_waitcnt vmcnt(4)" ::: "memory"); } });
  }
#undef DO_PHASE

  // ---- fused LSTM epilogue: compute + LDS-staged coalesced stores ----
  __syncthreads();                               // GEMM LDS fully retired; reuse
  char* base = (char*)&lds[0][0][0];
  unsigned short* hS = (unsigned short*)base;            // [256][64] u16 (STAGE1)
  unsigned short* cS = (unsigned short*)(base + 32768);  // [256][64] u16 (STAGE1)
  float*          hF = (float*)base;                     // [256][64] f32 (STAGE2)
  float* xw = (float*)(base + 65536) + wid * 256;        // per-wave transpose pad

  const int cs = lane & 3;
  const int er = (lane >> 4) << 2;
  const int uq = (lane >> 2) & 3;

  float cold[8][4];
#pragma unroll
  for (int mi = 0; mi < 8; ++mi)
#pragma unroll
    for (int ni = 0; ni < 4; ++ni) {
      const int R = row0 + wr * 128 + mi * 16 + er + cs;
      const int U = ((col0 + wc * 64 + ni * 16) >> 2) + uq;
      cold[mi][ni] = Cst[(size_t)R * 1024 + U];
    }

#pragma unroll
  for (int mi = 0; mi < 8; ++mi)
#pragma unroll
    for (int ni = 0; ni < 4; ++ni) {
      __builtin_amdgcn_wave_barrier();
      *(f32x4*)(xw + lane * 4) = acc[mi][ni];
      __builtin_amdgcn_wave_barrier();
      __builtin_amdgcn_sched_barrier(0);
      const int qb = (lane & 60) * 4;
      const float g0 = xw[qb + 0  + cs];
      const float g1 = xw[qb + 4  + cs];
      const float g2 = xw[qb + 8  + cs];
      const float g3 = xw[qb + 12 + cs];
      __builtin_amdgcn_wave_barrier();
      const int R = row0 + wr * 128 + mi * 16 + er + cs;
      const int U = ((col0 + wc * 64 + ni * 16) >> 2) + uq;
      const f32x4 b4 = *(const f32x4*)(ib + 4 * U);
      const float gi = g0 + b4[0];
      const float gf = g1 + b4[1];
      const float gg = g2 + b4[2];
      const float go = g3 + b4[3];
      const float cn = sigm(gf) * cold[mi][ni] + sigm(gi) * tanhx(gg);
      const float hn = sigm(go) * tanhx(cn);
      Cst[(size_t)R * 1024 + U] = cn;            // scattered (kept)
      const int Rl = wr * 128 + mi * 16 + er + cs;
      const int Ul = wc * 16 + ni * 4 + uq;
      if (STAGE == 1) {
        hS[Rl * 64 + Ul] = f2h(hn);
        cS[Rl * 64 + Ul] = f2h(cn);
      } else {
        hF[Rl * 64 + Ul] = hn;
      }
    }
  __syncthreads();

  const int U0 = col0 >> 2;
  if (STAGE == 1) {
#pragma unroll
    for (int it = 0; it < 4; ++it) {             // 2048 chunks of 16B
      const int idx = it * 512 + tid;
      const int r = idx >> 3, o = idx & 7;
      const int4 hv = *(const int4*)((char*)hS + idx * 16);
      const int4 cv = *(const int4*)((char*)cS + idx * 16);
      *(int4*)(P0 + (size_t)(row0 + r) * 2048 + U0 + o * 8)        = hv;  // hc.h
      *(int4*)(P0 + (size_t)(row0 + r) * 2048 + 1024 + U0 + o * 8) = cv;  // hc.c
      *(int4*)(P1 + (size_t)(row0 + r) * 2048 + 1024 + U0 + o * 8) = hv;  // gA_next.h
      *(int4*)(P2 + (size_t)(row0 + r) * 1024 + U0 + o * 8)        = hv;  // mid(t)
    }
  } else {
#pragma unroll
    for (int it = 0; it < 8; ++it) {             // 4096 chunks of 16B
      const int idx = it * 512 + tid;
      const int r = idx >> 4, o = idx & 15;
      const f32x4 hv = *(const f32x4*)((char*)hF + idx * 16);
      *(f32x4*)(F0 + (size_t)(row0 + r) * 1024 + U0 + o * 4) = hv;        // h2 f32
      uint2 pk;
      pk.x = (unsigned)f2h(hv[0]) | ((unsigned)f2h(hv[1]) << 16);
      pk.y = (unsigned)f2h(hv[2]) | ((unsigned)f2h(hv[3]) << 16);
      *(uint2*)(P0 + (size_t)(row0 + r) * 1024 + U0 + o * 4) = pk;        // h2b
    }
  }
}

// ---------------------------------------------------------------------------
// Score GEMM: 128x64 tile, 256 thr (4 waves 2Mx2N), 512 blocks (2/CU).
// Double-buffered 2-phase/K-tile, st_16x32 swizzle, counted vmcnt(2).
// Epilogue: gA[row,col] = f2h( x[row,col] * tanh(acc + b_sa[col]) ).
// ---------------------------------------------------------------------------
__global__ __launch_bounds__(256, 2)
void gemm_score2ph(const unsigned short* A0, int lda0, int K0,
                   const unsigned short* A1, int lda1,
                   const unsigned short* Bw, int K,
                   const float* bias, const unsigned short* X,
                   unsigned short* OutG)
{
  __shared__ unsigned short lds[2][12288];  // [buf][A 128x64 (16KB) | B 64x64 (8KB)]
  const int tid  = threadIdx.x;
  const int wid  = tid >> 6;
  const int lane = tid & 63;
  const int wr = wid >> 1;          // 0..1 (M) -> 64 rows each
  const int wc = wid & 1;           // 0..1 (N) -> 32 cols each
  const int NT = K >> 6;

  // XCD swizzle (grid 16x32 = 512 blocks, %8==0)
  const int bid = blockIdx.y * gridDim.x + blockIdx.x;
  const int cpx = (gridDim.x * gridDim.y) >> 3;
  const int swz = (bid & 7) * cpx + (bid >> 3);
  const int row0 = (swz / gridDim.x) * 128;
  const int col0 = (swz % gridDim.x) * 64;

  auto stage_A = [&](int bb, int kt) {           // 16KB: 4 issues
    const int k0 = kt * 64;
    const unsigned short* Ap; int lda, kc;
    if (k0 < K0) { Ap = A0; lda = lda0; kc = k0; }
    else         { Ap = A1; lda = lda1; kc = k0 - K0; }
#pragma unroll
    for (int i = 0; i < 4; ++i) {
      const int x  = (i * 256 + tid) * 16;
      const int xs = x ^ (((x >> 9) & 1) << 5);
      const int r  = xs >> 7;                    // 0..127
      const int cb = xs & 127;
      const unsigned short* src = Ap + (size_t)(row0 + r) * lda + kc + (cb >> 1);
      __builtin_amdgcn_global_load_lds((const AS1 void*)src,
          (AS3 void*)((char*)&lds[bb][0] + i * 4096 + wid * 1024), 16, 0, 0);
    }
  };
  auto stage_B = [&](int bb, int kt) {           // 8KB: 2 issues
    const int k0 = kt * 64;
#pragma unroll
    for (int i = 0; i < 2; ++i) {
      const int x  = (i * 256 + tid) * 16;
      const int xs = x ^ (((x >> 9) & 1) << 5);
      const int r  = xs >> 7;                    // 0..63
      const int cb = xs & 127;
      const unsigned short* src = Bw + (size_t)(col0 + r) * K + k0 + (cb >> 1);
      __builtin_amdgcn_global_load_lds((const AS1 void*)src,
          (AS3 void*)((char*)&lds[bb][0] + 16384 + i * 4096 + wid * 1024), 16, 0, 0);
    }
  };

  const int frow = lane & 15;
  const int axor = ((lane >> 2) & 1) << 5;
  const int abase = ((((wr * 64 + frow) << 7) + ((lane >> 4) << 4))) ^ axor;
  const int bbase = ((((wc * 32 + frow) << 7) + ((lane >> 4) << 4))) ^ axor;

  const f32x4 zero = {0.f, 0.f, 0.f, 0.f};
  f32x4 acc[4][2];
#pragma unroll
  for (int i = 0; i < 4; ++i)
#pragma unroll
    for (int j = 0; j < 2; ++j) acc[i][j] = zero;

  // prologue: A0,B0 + B1; wait leave B1 in flight
  stage_A(0, 0);
  stage_B(0, 0);
  if (NT > 1) stage_B(1, 1);
  asm volatile("s_waitcnt vmcnt(2)" ::: "memory");
  __builtin_amdgcn_s_barrier();

  for (int kt = 0; kt < NT; ++kt) {
    const int cur = kt & 1;
    const char* ldsA = (const char*)&lds[cur][0];
    const char* ldsB = ldsA + 16384;
    // ---- phase 0: B frags + A frags mi0,1 ; stage A(kt+1) ; MFMA mi0,1 ----
    f16x8 bv[2][2];
#pragma unroll
    for (int n = 0; n < 2; ++n) {
      bv[n][0] = *(const f16x8*)(ldsB + bbase + n * 2048);
      bv[n][1] = *(const f16x8*)(ldsB + bbase + n * 2048 + 64);
    }
    f16x8 a00 = *(const f16x8*)(ldsA + abase);
    f16x8 a01 = *(const f16x8*)(ldsA + abase + 64);
    f16x8 a10 = *(const f16x8*)(ldsA + abase + 2048);
    f16x8 a11 = *(const f16x8*)(ldsA + abase + 2048 + 64);
    if (kt + 1 < NT) stage_A(cur ^ 1, kt + 1);
    __builtin_amdgcn_s_barrier();
    asm volatile("s_waitcnt lgkmcnt(0)" ::: "memory");
    __builtin_amdgcn_sched_barrier(0);
    __builtin_amdgcn_s_setprio(1);
#pragma unroll
    for (int n = 0; n < 2; ++n) {
      acc[0][n] = __builtin_amdgcn_mfma_f32_16x16x32_f16(a00, bv[n][0], acc[0][n], 0, 0, 0);
      acc[0][n] = __builtin_amdgcn_mfma_f32_16x16x32_f16(a01, bv[n][1], acc[0][n], 0, 0, 0);
      acc[1][n] = __builtin_amdgcn_mfma_f32_16x16x32_f16(a10, bv[n][0], acc[1][n], 0, 0, 0);
      acc[1][n] = __builtin_amdgcn_mfma_f32_16x16x32_f16(a11, bv[n][1], acc[1][n], 0, 0, 0);
    }
    __builtin_amdgcn_s_setprio(0);
    __builtin_amdgcn_s_barrier();
    // ---- phase 1: A frags mi2,3 ; stage B(kt+2) ; MFMA mi2,3 ; vmcnt ----
    f16x8 a20 = *(const f16x8*)(ldsA + abase + 2 * 2048);
    f16x8 a21 = *(const f16x8*)(ldsA + abase + 2 * 2048 + 64);
    f16x8 a30 = *(const f16x8*)(ldsA + abase + 3 * 2048);
    f16x8 a31 = *(const f16x8*)(ldsA + abase + 3 * 2048 + 64);
    if (kt + 2 < NT) stage_B(cur, kt + 2);
    __builtin_amdgcn_s_barrier();
    asm volatile("s_waitcnt lgkmcnt(0)" ::: "memory");
    __builtin_amdgcn_sched_barrier(0);
    __builtin_amdgcn_s_setprio(1);
#pragma unroll
    for (int n = 0; n < 2; ++n) {
      acc[2][n] = __builtin_amdgcn_mfma_f32_16x16x32_f16(a20, bv[n][0], acc[2][n], 0, 0, 0);
      acc[2][n] = __builtin_amdgcn_mfma_f32_16x16x32_f16(a21, bv[n][1], acc[2][n], 0, 0, 0);
      acc[3][n] = __builtin_amdgcn_mfma_f32_16x16x32_f16(a30, bv[n][0], acc[3][n], 0, 0, 0);
      acc[3][n] = __builtin_amdgcn_mfma_f32_16x16x32_f16(a31, bv[n][1], acc[3][n], 0, 0, 0);
    }
    __builtin_amdgcn_s_setprio(0);
    if (kt >= NT - 2) { asm volatile("s_waitcnt vmcnt(0)" ::: "memory"); }
    else              { asm volatile("s_waitcnt vmcnt(2)" ::: "memory"); }
    __builtin_amdgcn_s_barrier();
  }

  // ---- fused score epilogue ----
  const int er = (lane >> 4) << 2;
#pragma unroll
  for (int mi = 0; mi < 4; ++mi)
#pragma unroll
    for (int ni = 0; ni < 2; ++ni) {
      const int row = row0 + wr * 64 + mi * 16 + er;
      const int col = col0 + wc * 32 + ni * 16 + frow;
      const float bs = bias[col];
#pragma unroll
      for (int r = 0; r < 4; ++r) {
        const float v = tanhx(acc[mi][ni][r] + bs);
        const float xv = h2f(X[(size_t)(row + r) * 1024 + col]);
        OutG[(size_t)(row + r) * 2048 + col] = f2h(xv * v);
      }
    }
}

// ---------------------------------------------------------------------------
// Prep kernels
// ---------------------------------------------------------------------------
__global__ void f2h_copy(const float* src, unsigned short* dst, int n) {
  const int i = blockIdx.x * 256 + threadIdx.x;
  if (i < n) dst[i] = f2h(src[i]);
}

// dst (4096,2048) gate-interleaved: dst[4u+g] = [Wih[g*1024+u] | Whh[g*1024+u]]
__global__ void cat_w_int(const float* wih, const float* whh, unsigned short* dst) {
  const int i = blockIdx.x * 256 + threadIdx.x;   // 4096*2048
  const int n = i >> 11, k = i & 2047;
  const int u = n >> 2, g = n & 3;
  const int src = g * 1024 + u;
  dst[i] = f2h(k < 1024 ? wih[src * 1024 + k] : whh[src * 1024 + (k - 1024)]);
}

// interleaved bias: ib[4u+g] = bih[g*1024+u] + bhh[g*1024+u]
__global__ void prep_bias(const float* bih, const float* bhh, float* ib) {
  const int i = blockIdx.x * 256 + threadIdx.x;   // 4096
  const int u = i >> 2, g = i & 3;
  ib[i] = bih[g * 1024 + u] + bhh[g * 1024 + u];
}

// vectorized p_q copy with (b,s,.) -> (t,b,.) transpose
__global__ void copy_pq(const float* pq, unsigned short* inb) {
  const int i4 = blockIdx.x * 256 + threadIdx.x;  // float4 index
  const float4 v = ((const float4*)pq)[i4];
  const int base = i4 * 4;
  const float vv[4] = {v.x, v.y, v.z, v.w};
#pragma unroll
  for (int e = 0; e < 4; ++e) {
    const int idx = base + e;
    const int bt = idx / 1003;
    const int j = idx - bt * 1003;
    const int b = bt / 15;
    const int t = bt - b * 15;
    inb[((size_t)t * BATCH + b) * 1024 + j] = f2h(vv[e]);
  }
}

// cfg linear (10 outputs, K=128) + 11 embedding cols; one wave per (b,t) row
__global__ void cfg_emb(const float* cfg, const int* tim,
                        const float* Wc, const float* bc,
                        const float* eh, const float* ew, const float* es,
                        unsigned short* inb)
{
  const int wv = (blockIdx.x * 256 + threadIdx.x) >> 6;  // row = b*15+t
  const int lane = threadIdx.x & 63;
  const int b = wv / 15, t = wv - b * 15;
  const float* cp = cfg + (size_t)wv * 128;
  const float c0 = cp[lane], c1v = cp[lane + 64];
  unsigned short* dst = inb + ((size_t)t * BATCH + b) * 1024;
#pragma unroll
  for (int g = 0; g < 10; ++g) {
    float v = fmaf(c0, Wc[g * 128 + lane], c1v * Wc[g * 128 + 64 + lane]);
    v += __shfl_xor(v, 32); v += __shfl_xor(v, 16); v += __shfl_xor(v, 8);
    v += __shfl_xor(v, 4);  v += __shfl_xor(v, 2);  v += __shfl_xor(v, 1);
    if (lane == 0) dst[1003 + g] = f2h(v + bc[g]);
  }
  if (lane < 5)       dst[1013 + lane] = f2h(eh[tim[wv * 3 + 0] * 5 + lane]);
  else if (lane < 8)  dst[1018 + (lane - 5)] = f2h(ew[tim[wv * 3 + 1] * 3 + (lane - 5)]);
  else if (lane < 11) dst[1021 + (lane - 8)] = f2h(es[tim[wv * 3 + 2] * 3 + (lane - 8)]);
}

// ---------------------------------------------------------------------------
// BatchNorm over (B,H) per s
// ---------------------------------------------------------------------------
__global__ void bn_partial(const unsigned short* mid, float* part) {
  const int t = blockIdx.y, blk = blockIdx.x, tid = threadIdx.x;
  const unsigned short* p = mid + (size_t)t * BATCH * 1024;
  float s = 0.f, ss = 0.f;
  for (int i = blk * 256 + tid; i < BATCH * 1024; i += 128 * 256) {
    const float v = h2f(p[i]);
    s += v; ss += v * v;
  }
  for (int o = 32; o > 0; o >>= 1) { s += __shfl_down(s, o); ss += __shfl_down(ss, o); }
  __shared__ float sm[8];
  if ((tid & 63) == 0) { sm[(tid >> 6) * 2] = s; sm[(tid >> 6) * 2 + 1] = ss; }
  __syncthreads();
  if (tid == 0) {
    part[(t * 128 + blk) * 2]     = sm[0] + sm[2] + sm[4] + sm[6];
    part[(t * 128 + blk) * 2 + 1] = sm[1] + sm[3] + sm[5] + sm[7];
  }
}

__global__ void bn_final(const float* part, const float* gamma, const float* beta, float* scsh) {
  const int t = blockIdx.x, tid = threadIdx.x;  // 128 threads
  float s = part[(t * 128 + tid) * 2], ss = part[(t * 128 + tid) * 2 + 1];
  for (int o = 32; o > 0; o >>= 1) { s += __shfl_down(s, o); ss += __shfl_down(ss, o); }
  __shared__ float sm[4];
  if ((tid & 63) == 0) { sm[(tid >> 6) * 2] = s; sm[(tid >> 6) * 2 + 1] = ss; }
  __syncthreads();
  if (tid == 0) {
    const float S = sm[0] + sm[2], SS = sm[1] + sm[3];
    const float inv = 1.f / (float)(BATCH * 1024);
    const float mu = S * inv;
    const float var = SS * inv - mu * mu;
    const float rstd = rsqrtf(var + 1e-5f);
    const float sc = rstd * gamma[t];
    scsh[t * 2] = sc;
    scsh[t * 2 + 1] = beta[t] - mu * sc;
  }
}

__global__ void bn_apply(unsigned short* mid, const float* scsh) {
  const int t = blockIdx.y;
  const int i = blockIdx.x * 256 + threadIdx.x;
  unsigned short* p = mid + (size_t)t * BATCH * 1024;
  p[i] = f2h(h2f(p[i]) * scsh[t * 2] + scsh[t * 2 + 1]);
}

// ---------------------------------------------------------------------------
// Stage-2 attention/proj
// ---------------------------------------------------------------------------
__global__ void att_proj(const float* h2, const float* c2, const unsigned short* xn,
                         const float* Wta, const float* bta, const float* Wihd,
                         float* att2, float* proj, int t)
{
  const int b = blockIdx.x, tid = threadIdx.x;   // 256 threads
  const float* h = h2 + (size_t)b * 1024;
  const float* c = c2 + (size_t)b * 1024;
  const unsigned short* x = xn + (size_t)b * 1024;
  float a = 0.f, p0 = 0.f, p1 = 0.f, p2 = 0.f, p3 = 0.f;
  for (int j = tid; j < 1024; j += 256) {
    const float hv = h[j], cv = c[j], xv = h2f(x[j]);
    a  += hv * Wta[j] + cv * Wta[1024 + j] + xv * Wta[2048 + j];
    p0 += hv * Wihd[j];
    p1 += hv * Wihd[1024 + j];
    p2 += hv * Wihd[2048 + j];
    p3 += hv * Wihd[3072 + j];
  }
  for (int o = 32; o > 0; o >>= 1) {
    a  += __shfl_down(a, o);  p0 += __shfl_down(p0, o); p1 += __shfl_down(p1, o);
    p2 += __shfl_down(p2, o); p3 += __shfl_down(p3, o);
  }
  __shared__ float sm[4][5];
  if ((tid & 63) == 0) {
    const int w = tid >> 6;
    sm[w][0] = a; sm[w][1] = p0; sm[w][2] = p1; sm[w][3] = p2; sm[w][4] = p3;
  }
  __syncthreads();
  if (tid == 0) {
    att2[b * SEQ + t] = tanhx(sm[0][0] + sm[1][0] + sm[2][0] + sm[3][0] + bta[0]);
    float* pp = proj + ((size_t)b * SEQ + t) * 4;
    pp[0] = sm[0][1] + sm[1][1] + sm[2][1] + sm[3][1];
    pp[1] = sm[0][2] + sm[1][2] + sm[2][2] + sm[3][2];
    pp[2] = sm[0][3] + sm[1][3] + sm[2][3] + sm[3][3];
    pp[3] = sm[0][4] + sm[1][4] + sm[2][4] + sm[3][4];
  }
}

// ---------------------------------------------------------------------------
// Stage 3: chunked pipelined-Jacobi scalar LSTM (exact after 8 iters)
// ---------------------------------------------------------------------------
__global__ __launch_bounds__(256) void lstm3_par(
    const float* proj, const float* Whhd,
    const float* bihd, const float* bhhd, float* out1d)
{
  const int s = blockIdx.x;            // 0..14
  const int tid = threadIdx.x;         // 0..255
  constexpr int CH = BATCH / 256;      // 16
  const float wi = Whhd[0], wf = Whhd[1], wg = Whhd[2], wo = Whhd[3];
  const float bi = bihd[0] + bhhd[0], bf_ = bihd[1] + bhhd[1];
  const float bg = bihd[2] + bhhd[2], bo = bihd[3] + bhhd[3];
  const float4* p4 = (const float4*)proj;
  float4 p[CH];
#pragma unroll
  for (int u = 0; u < CH; ++u) p[u] = p4[(tid * CH + u) * SEQ + s];
  __shared__ float Hb[257], Cb[257];
  Hb[tid] = 0.f; Cb[tid] = 0.f;
  if (tid == 255) { Hb[256] = 0.f; Cb[256] = 0.f; }
  __syncthreads();
  float h, c;
  for (int it = 0; it < 8; ++it) {
    h = Hb[tid]; c = Cb[tid];
#pragma unroll
    for (int u = 0; u < CH; ++u) {
      const float gi = fmaf(h, wi, p[u].x + bi);
      const float gf = fmaf(h, wf, p[u].y + bf_);
      const float gg = fmaf(h, wg, p[u].z + bg);
      const float go = fmaf(h, wo, p[u].w + bo);
      c = sigm(gf) * c + sigm(gi) * tanhx(gg);
      h = sigm(go) * tanhx(c);
    }
    __syncthreads();
    Hb[tid + 1] = h; Cb[tid + 1] = c;
    __syncthreads();
  }
  h = Hb[tid]; c = Cb[tid];
#pragma unroll
  for (int u = 0; u < CH; ++u) {
    const float gi = fmaf(h, wi, p[u].x + bi);
    const float gf = fmaf(h, wf, p[u].y + bf_);
    const float gg = fmaf(h, wg, p[u].z + bg);
    const float go = fmaf(h, wo, p[u].w + bo);
    c = sigm(gf) * c + sigm(gi) * tanhx(gg);
    h = sigm(go) * tanhx(c);
    out1d[(tid * CH + u) * SEQ + s] = h;
  }
}

__global__ void finalize_k(const float* att2, const float* out1d, float* out) {
  const int b = blockIdx.x * 64 + threadIdx.x;
  const float* a = att2 + b * SEQ;
  const float* o = out1d + b * SEQ;
  float m = -1e30f;
  for (int s = 0; s < SEQ; ++s) m = fmaxf(m, a[s]);
  float den = 0.f, num = 0.f;
  for (int s = 0; s < SEQ; ++s) {
    const float e = __expf(a[s] - m);
    den += e; num += e * o[s];
  }
  out[b] = num / den;
}

// ---------------------------------------------------------------------------
extern "C" void kernel_launch(void* const* d_in, const int* in_sizes, int n_in,
                              void* d_out, int out_size, void* d_ws, size_t ws_size,
                              hipStream_t stream)
{
  (void)in_sizes; (void)n_in; (void)out_size; (void)ws_size;
  const float* in_pq   = (const float*)d_in[0];
  const float* in_cfg  = (const float*)d_in[1];
  const int*   in_time = (const int*)d_in[2];
  const float* W_cfg   = (const float*)d_in[3];
  const float* b_cfg   = (const float*)d_in[4];
  const float* emb_h   = (const float*)d_in[5];
  const float* emb_w   = (const float*)d_in[6];
  const float* emb_s   = (const float*)d_in[7];
  const float* W_sa    = (const float*)d_in[8];
  const float* b_sa    = (const float*)d_in[9];
  const float* Wih_s   = (const float*)d_in[10];
  const float* Whh_s   = (const float*)d_in[11];
  const float* bih_s   = (const float*)d_in[12];
  const float* bhh_s   = (const float*)d_in[13];
  const float* Wih_t   = (const float*)d_in[14];
  const float* Whh_t   = (const float*)d_in[15];
  const float* bih_t   = (const float*)d_in[16];
  const float* bhh_t   = (const float*)d_in[17];
  const float* W_ta    = (const float*)d_in[18];
  const float* b_ta    = (const float*)d_in[19];
  const float* gamma   = (const float*)d_in[20];
  const float* beta    = (const float*)d_in[21];
  const float* Wih_d   = (const float*)d_in[22];
  const float* Whh_d   = (const float*)d_in[23];
  const float* bih_d   = (const float*)d_in[24];
  const float* bhh_d   = (const float*)d_in[25];
  float* out = (float*)d_out;

  char* w = (char*)d_ws;
  size_t off = 0;
  auto alloc = [&](size_t bytes) -> char* {
    char* p = w + off;
    off = (off + bytes + 255) & ~(size_t)255;
    return p;
  };
  unsigned short* inb  = (unsigned short*)alloc((size_t)SEQ * BATCH * 1024 * 2); // x -> mid -> mid_norm
  unsigned short* hc   = (unsigned short*)alloc((size_t)BATCH * 2048 * 2);       // [h|c] fp16 (stage1)
  unsigned short* gA0  = (unsigned short*)alloc((size_t)BATCH * 2048 * 2);       // [xs|h] ping
  unsigned short* gA1  = (unsigned short*)alloc((size_t)BATCH * 2048 * 2);       // [xs|h] pong
  float*          c1   = (float*)alloc((size_t)BATCH * 1024 * 4);
  unsigned short* h2b0 = (unsigned short*)alloc((size_t)BATCH * 1024 * 2);
  unsigned short* h2b1 = (unsigned short*)alloc((size_t)BATCH * 1024 * 2);
  float*          h2f_ = (float*)alloc((size_t)BATCH * 1024 * 4);
  float*          c2f  = (float*)alloc((size_t)BATCH * 1024 * 4);
  unsigned short* wsab = (unsigned short*)alloc((size_t)1024 * 3072 * 2);
  unsigned short* w1   = (unsigned short*)alloc((size_t)4096 * 2048 * 2);
  unsigned short* w2   = (unsigned short*)alloc((size_t)4096 * 2048 * 2);
  float*          ib1  = (float*)alloc(4096 * 4);
  float*          ib2  = (float*)alloc(4096 * 4);
  float*          part = (float*)alloc(15 * 128 * 2 * 4);
  float*          scsh = (float*)alloc(15 * 2 * 4);
  float*          att2 = (float*)alloc((size_t)BATCH * SEQ * 4);
  float*          proj = (float*)alloc((size_t)BATCH * SEQ * 4 * 4);
  float*          o1d  = (float*)alloc((size_t)BATCH * SEQ * 4);

  unsigned short* gAbuf[2]  = {gA0, gA1};
  unsigned short* h2bbuf[2] = {h2b0, h2b1};

  // zero recurrent state each call (deterministic)
  hipMemsetAsync(hc,   0, (size_t)BATCH * 2048 * 2, stream);
  hipMemsetAsync(gA0,  0, (size_t)BATCH * 2048 * 2, stream);
  hipMemsetAsync(c1,   0, (size_t)BATCH * 1024 * 4, stream);
  hipMemsetAsync(h2b0, 0, (size_t)BATCH * 1024 * 2, stream);
  hipMemsetAsync(c2f,  0, (size_t)BATCH * 1024 * 4, stream);

  // weight conversion + input assembly
  f2h_copy<<<(1024 * 3072) / 256, 256, 0, stream>>>(W_sa, wsab, 1024 * 3072);
  cat_w_int<<<(4096 * 2048) / 256, 256, 0, stream>>>(Wih_s, Whh_s, w1);
  cat_w_int<<<(4096 * 2048) / 256, 256, 0, stream>>>(Wih_t, Whh_t, w2);
  prep_bias<<<16, 256, 0, stream>>>(bih_s, bhh_s, ib1);
  prep_bias<<<16, 256, 0, stream>>>(bih_t, bhh_t, ib2);
  copy_pq<<<(BATCH * SEQ * 1003 / 4) / 256, 256, 0, stream>>>(in_pq, inb);
  cfg_emb<<<(BATCH * SEQ) / 4, 256, 0, stream>>>(in_cfg, in_time, W_cfg, b_cfg,
                                                 emb_h, emb_w, emb_s, inb);

  // ---- stage 1 (2ph score GEMM + fused-LSTM 8-phase gates GEMM) ----
  for (int t = 0; t < SEQ; ++t) {
    unsigned short* xt = inb + (size_t)t * BATCH * 1024;
    gemm_score2ph<<<dim3(1024 / 64, BATCH / 128), 256, 0, stream>>>(
        hc, 2048, 2048, xt, 1024, wsab, 3072, b_sa, xt, gAbuf[t & 1]);
    gemm_lstm256<1><<<dim3(4096 / 256, BATCH / 256), 512, 0, stream>>>(
        gAbuf[t & 1], 2048, 2048, gAbuf[t & 1], 2048, w1, 2048,
        ib1, c1, hc, gAbuf[(t + 1) & 1], xt, nullptr);
  }

  // ---- batchnorm over (B,H) per s ----
  bn_partial<<<dim3(128, SEQ), 256, 0, stream>>>(inb, part);
  bn_final<<<SEQ, 128, 0, stream>>>(part, gamma, beta, scsh);
  bn_apply<<<dim3((BATCH * 1024) / 256, SEQ), 256, 0, stream>>>(inb, scsh);

  // ---- stage 2 (fused-LSTM 8-phase gates GEMM + attention/proj) ----
  for (int t = 0; t < SEQ; ++t) {
    const unsigned short* xt = inb + (size_t)t * BATCH * 1024;
    gemm_lstm256<2><<<dim3(4096 / 256, BATCH / 256), 512, 0, stream>>>(
        xt, 1024, 1024, h2bbuf[t & 1], 1024, w2, 2048,
        ib2, c2f, h2bbuf[(t + 1) & 1], nullptr, nullptr, h2f_);
    att_proj<<<BATCH, 256, 0, stream>>>(h2f_, c2f, xt, W_ta, b_ta, Wih_d, att2, proj, t);
  }

  // ---- stage 3 + output ----
  lstm3_par<<<SEQ, 256, 0, stream>>>(proj, Whh_d, bih_d, bhh_d, o1d);
  finalize_k<<<BATCH / 64, 64, 0, stream>>>(att2, o1d, out);
}

// Round 9
// 3434.369 us; speedup vs baseline: 1.2246x; 1.0319x over previous
//
#include <hip/hip_runtime.h>

#define AS1 __attribute__((address_space(1)))
#define AS3 __attribute__((address_space(3)))

typedef __attribute__((ext_vector_type(8))) _Float16 f16x8;
typedef __attribute__((ext_vector_type(4))) float f32x4;

static constexpr int BATCH = 4096;
static constexpr int SEQ   = 15;

__device__ __forceinline__ float h2f(unsigned short u) {
  return (float)__builtin_bit_cast(_Float16, u);
}
__device__ __forceinline__ unsigned short f2h(float f) {
  return __builtin_bit_cast(unsigned short, (_Float16)f);   // RNE
}
__device__ __forceinline__ float frcp(float x) { return __builtin_amdgcn_rcpf(x); }
__device__ __forceinline__ float sigm(float x)  { return frcp(1.0f + __expf(-x)); }
__device__ __forceinline__ float tanhx(float x) { return 1.0f - 2.0f * frcp(1.0f + __expf(2.0f * x)); }

// ---------------------------------------------------------------------------
// 8-phase 256x256 GEMM with fused LSTM epilogue (T2+T3+T4+T5).
// STAGE 1: writes hc/[h|c], gA_next h-half, mid(t) (all LDS-staged coalesced).
// STAGE 2: writes h2b_next + per-colblock attention/proj partials redT[t]
//          (h,c consumed in-register; att x-term precomputed by xdot_k).
// ---------------------------------------------------------------------------
template<int STAGE>
__global__ __launch_bounds__(512, 2)
void gemm_lstm256(const unsigned short* A0, int lda0, int K0,
                  const unsigned short* A1, int lda1,
                  const unsigned short* Bw, int K,
                  const float* ib, float* Cst,
                  unsigned short* P0, unsigned short* P1, unsigned short* P2,
                  const float* Wta, const float* Wihd, float* redG)
{
  __shared__ unsigned short lds[2][2][16384];   // [buf][A/B][256 rows x 64 cols]
  const int tid  = threadIdx.x;
  const int wid  = tid >> 6;
  const int lane = tid & 63;
  const int wr = wid >> 2;          // 0..1 (M)
  const int wc = wid & 3;           // 0..3 (N)
  const int NT = K >> 6;

  // XCD swizzle (grid 16x16 = 256 blocks, %8==0)
  const int bid = blockIdx.y * gridDim.x + blockIdx.x;
  const int cpx = (gridDim.x * gridDim.y) >> 3;
  const int swz = (bid & 7) * cpx + (bid >> 3);
  const int row0 = (swz / gridDim.x) * 256;
  const int col0 = (swz % gridDim.x) * 256;

  auto stage_half = [&](int bb, int mat, int hh, int kt) {
    const int k0 = kt * 64;
    const unsigned short* Ap; int lda, kc, rb;
    if (mat == 0) {
      if (k0 < K0) { Ap = A0; lda = lda0; kc = k0; }
      else         { Ap = A1; lda = lda1; kc = k0 - K0; }
      rb = row0;
    } else { Ap = Bw; lda = K; kc = k0; rb = col0; }
#pragma unroll
    for (int i = 0; i < 2; ++i) {
      const int x  = (tid + i * 512) * 16;             // LDS byte in 16KB half
      const int xs = x ^ (((x >> 9) & 1) << 5);        // logical byte (st_16x32)
      const int r  = hh * 128 + (xs >> 7);
      const int cb = xs & 127;
      const unsigned short* src = Ap + (size_t)(rb + r) * lda + kc + (cb >> 1);
      __builtin_amdgcn_global_load_lds((const AS1 void*)src,
          (AS3 void*)((char*)&lds[bb][mat][0] + hh * 16384 + wid * 1024 + i * 8192),
          16, 0, 0);
    }
  };

  const int frow = lane & 15;
  const int axor = ((lane >> 2) & 1) << 5;
  const int abase = ((((wr * 128 + frow) << 7) + (((lane >> 4) & 3) << 4))) ^ axor;
  const int bbase = ((((wc * 64  + frow) << 7) + (((lane >> 4) & 3) << 4))) ^ axor;

  const f32x4 zero = {0.f, 0.f, 0.f, 0.f};
  f32x4 acc[8][4];
#pragma unroll
  for (int i = 0; i < 8; ++i)
#pragma unroll
    for (int j = 0; j < 4; ++j) acc[i][j] = zero;

  stage_half(0, 0, 0, 0);
  stage_half(0, 0, 1, 0);
  stage_half(0, 1, 0, 0);
  stage_half(0, 1, 1, 0);
  if (NT > 1) { stage_half(1, 1, 0, 1); stage_half(1, 1, 1, 1); }
  asm volatile("s_waitcnt vmcnt(4)" ::: "memory");
  __builtin_amdgcn_s_barrier();

#define DO_PHASE(MB, STG, VMW)                                                        \
  {                                                                                   \
    const f16x8 a0 = *(const f16x8*)(ldsA + abase + (MB)     * 2048);                 \
    const f16x8 a1 = *(const f16x8*)(ldsA + abase + (MB)     * 2048 + 64);            \
    const f16x8 a2 = *(const f16x8*)(ldsA + abase + (MB + 1) * 2048);                 \
    const f16x8 a3 = *(const f16x8*)(ldsA + abase + (MB + 1) * 2048 + 64);            \
    STG;                                                                              \
    __builtin_amdgcn_s_barrier();                                                     \
    asm volatile("s_waitcnt lgkmcnt(0)" ::: "memory");                                \
    __builtin_amdgcn_sched_barrier(0);                                                \
    __builtin_amdgcn_s_setprio(1);                                                    \
    _Pragma("unroll")                                                                 \
    for (int n = 0; n < 4; ++n) {                                                     \
      acc[MB][n]     = __builtin_amdgcn_mfma_f32_16x16x32_f16(a0, bv[n][0], acc[MB][n],     0, 0, 0); \
      acc[MB][n]     = __builtin_amdgcn_mfma_f32_16x16x32_f16(a1, bv[n][1], acc[MB][n],     0, 0, 0); \
      acc[MB + 1][n] = __builtin_amdgcn_mfma_f32_16x16x32_f16(a2, bv[n][0], acc[MB + 1][n], 0, 0, 0); \
      acc[MB + 1][n] = __builtin_amdgcn_mfma_f32_16x16x32_f16(a3, bv[n][1], acc[MB + 1][n], 0, 0, 0); \
    }                                                                                 \
    __builtin_amdgcn_s_setprio(0);                                                    \
    VMW;                                                                              \
    __builtin_amdgcn_s_barrier();                                                     \
  }

  for (int kt = 0; kt < NT; ++kt) {
    const int cur = kt & 1;
    const char* ldsA = (const char*)&lds[cur][0][0];
    const char* ldsB = (const char*)&lds[cur][1][0];
    f16x8 bv[4][2];
#pragma unroll
    for (int n = 0; n < 4; ++n) {
      bv[n][0] = *(const f16x8*)(ldsB + bbase + n * 2048);
      bv[n][1] = *(const f16x8*)(ldsB + bbase + n * 2048 + 64);
    }
    DO_PHASE(0, { if (kt + 1 < NT) stage_half(cur ^ 1, 0, 0, kt + 1); }, { (void)0; });
    DO_PHASE(2, { if (kt + 1 < NT) stage_half(cur ^ 1, 0, 1, kt + 1); }, { (void)0; });
    DO_PHASE(4, { if (kt + 2 < NT) stage_half(cur,     1, 0, kt + 2); }, { (void)0; });
    DO_PHASE(6, { if (kt + 2 < NT) stage_half(cur,     1, 1, kt + 2); },
             { if (kt >= NT - 2) { asm volatile("s_waitcnt vmcnt(0)" ::: "memory"); }
               else              { asm volatile("s_waitcnt vmcnt(4)" ::: "memory"); } });
  }
#undef DO_PHASE

  // ---- fused LSTM epilogue ----
  __syncthreads();                               // GEMM LDS retired; reuse
  char* base = (char*)&lds[0][0][0];
  const int cs = lane & 3;
  const int er = (lane >> 4) << 2;
  const int uq = (lane >> 2) & 3;
  const int U0g = col0 >> 2;

  float cold[8][4];
#pragma unroll
  for (int mi = 0; mi < 8; ++mi)
#pragma unroll
    for (int ni = 0; ni < 4; ++ni) {
      const int R = row0 + wr * 128 + mi * 16 + er + cs;
      const int U = U0g + wc * 16 + ni * 4 + uq;
      cold[mi][ni] = Cst[(size_t)R * 1024 + U];
    }

  if constexpr (STAGE == 1) {
    unsigned short* hS = (unsigned short*)base;            // [256][64] u16
    unsigned short* cS = (unsigned short*)(base + 32768);  // [256][64] u16
    float* xw = (float*)(base + 65536) + wid * 256;
#pragma unroll
    for (int mi = 0; mi < 8; ++mi)
#pragma unroll
      for (int ni = 0; ni < 4; ++ni) {
        __builtin_amdgcn_wave_barrier();
        *(f32x4*)(xw + lane * 4) = acc[mi][ni];
        __builtin_amdgcn_wave_barrier();
        __builtin_amdgcn_sched_barrier(0);
        const int qb = (lane & 60) * 4;
        const float g0 = xw[qb + 0  + cs];
        const float g1 = xw[qb + 4  + cs];
        const float g2 = xw[qb + 8  + cs];
        const float g3 = xw[qb + 12 + cs];
        __builtin_amdgcn_wave_barrier();
        const int R = row0 + wr * 128 + mi * 16 + er + cs;
        const int U = U0g + wc * 16 + ni * 4 + uq;
        const f32x4 b4 = *(const f32x4*)(ib + 4 * U);
        const float cn = sigm(g1 + b4[1]) * cold[mi][ni]
                       + sigm(g0 + b4[0]) * tanhx(g2 + b4[2]);
        const float hn = sigm(g3 + b4[3]) * tanhx(cn);
        Cst[(size_t)R * 1024 + U] = cn;
        const int Rl = wr * 128 + mi * 16 + er + cs;
        const int Ul = wc * 16 + ni * 4 + uq;
        hS[Rl * 64 + Ul] = f2h(hn);
        cS[Rl * 64 + Ul] = f2h(cn);
      }
    __syncthreads();
#pragma unroll
    for (int it = 0; it < 4; ++it) {             // 2048 chunks of 16B
      const int idx = it * 512 + tid;
      const int r = idx >> 3, o = idx & 7;
      const int4 hv = *(const int4*)((char*)hS + idx * 16);
      const int4 cv = *(const int4*)((char*)cS + idx * 16);
      *(int4*)(P0 + (size_t)(row0 + r) * 2048 + U0g + o * 8)        = hv;  // hc.h
      *(int4*)(P0 + (size_t)(row0 + r) * 2048 + 1024 + U0g + o * 8) = cv;  // hc.c
      *(int4*)(P1 + (size_t)(row0 + r) * 2048 + 1024 + U0g + o * 8) = hv;  // gA_next.h
      *(int4*)(P2 + (size_t)(row0 + r) * 1024 + U0g + o * 8)        = hv;  // mid(t)
    }
  } else {
    unsigned short* hS = (unsigned short*)base;            // [256][64] u16
    float* xw  = (float*)(base + 32768) + wid * 256;
    float* wL  = (float*)(base + 40960);                   // 384 floats
    float* red = (float*)(base + 49152);                   // [4][256][5]
    if (tid < 64) {
      wL[tid]       = Wta[U0g + tid];
      wL[64 + tid]  = Wta[1024 + U0g + tid];
      wL[128 + tid] = Wihd[U0g + tid];
      wL[192 + tid] = Wihd[1024 + U0g + tid];
      wL[256 + tid] = Wihd[2048 + U0g + tid];
      wL[320 + tid] = Wihd[3072 + U0g + tid];
    }
    __syncthreads();
    float aH[8] = {}, q0[8] = {}, q1[8] = {}, q2[8] = {}, q3[8] = {};
#pragma unroll
    for (int mi = 0; mi < 8; ++mi)
#pragma unroll
      for (int ni = 0; ni < 4; ++ni) {
        __builtin_amdgcn_wave_barrier();
        *(f32x4*)(xw + lane * 4) = acc[mi][ni];
        __builtin_amdgcn_wave_barrier();
        __builtin_amdgcn_sched_barrier(0);
        const int qb = (lane & 60) * 4;
        const float g0 = xw[qb + 0  + cs];
        const float g1 = xw[qb + 4  + cs];
        const float g2 = xw[qb + 8  + cs];
        const float g3 = xw[qb + 12 + cs];
        __builtin_amdgcn_wave_barrier();
        const int R = row0 + wr * 128 + mi * 16 + er + cs;
        const int U = U0g + wc * 16 + ni * 4 + uq;
        const f32x4 b4 = *(const f32x4*)(ib + 4 * U);
        const float cn = sigm(g1 + b4[1]) * cold[mi][ni]
                       + sigm(g0 + b4[0]) * tanhx(g2 + b4[2]);
        const float hn = sigm(g3 + b4[3]) * tanhx(cn);
        Cst[(size_t)R * 1024 + U] = cn;
        const int Rl = wr * 128 + mi * 16 + er + cs;
        const int ul = wc * 16 + ni * 4 + uq;
        hS[Rl * 64 + ul] = f2h(hn);
        aH[mi] = fmaf(hn, wL[ul], fmaf(cn, wL[64 + ul], aH[mi]));
        q0[mi] = fmaf(hn, wL[128 + ul], q0[mi]);
        q1[mi] = fmaf(hn, wL[192 + ul], q1[mi]);
        q2[mi] = fmaf(hn, wL[256 + ul], q2[mi]);
        q3[mi] = fmaf(hn, wL[320 + ul], q3[mi]);
      }
    // reduce over the 4 uq lanes (unit axis within wave)
#pragma unroll
    for (int mi = 0; mi < 8; ++mi) {
      aH[mi] += __shfl_xor(aH[mi], 4); aH[mi] += __shfl_xor(aH[mi], 8);
      q0[mi] += __shfl_xor(q0[mi], 4); q0[mi] += __shfl_xor(q0[mi], 8);
      q1[mi] += __shfl_xor(q1[mi], 4); q1[mi] += __shfl_xor(q1[mi], 8);
      q2[mi] += __shfl_xor(q2[mi], 4); q2[mi] += __shfl_xor(q2[mi], 8);
      q3[mi] += __shfl_xor(q3[mi], 4); q3[mi] += __shfl_xor(q3[mi], 8);
    }
    if (uq == 0) {
#pragma unroll
      for (int mi = 0; mi < 8; ++mi) {
        const int r = wr * 128 + mi * 16 + er + cs;
        float* d = red + ((size_t)wc * 256 + r) * 5;
        d[0] = aH[mi]; d[1] = q0[mi]; d[2] = q1[mi]; d[3] = q2[mi]; d[4] = q3[mi];
      }
    }
    __syncthreads();
    const int cb = col0 >> 8;
    for (int idx = tid; idx < 1280; idx += 512) {
      const int r = idx / 5, k = idx - r * 5;
      const float s = red[(0 * 256 + r) * 5 + k] + red[(1 * 256 + r) * 5 + k]
                    + red[(2 * 256 + r) * 5 + k] + red[(3 * 256 + r) * 5 + k];
      redG[((size_t)(row0 + r) * 16 + cb) * 5 + k] = s;
    }
#pragma unroll
    for (int it = 0; it < 4; ++it) {             // h2b copy-out: 2048 x 16B
      const int idx = it * 512 + tid;
      const int r = idx >> 3, o = idx & 7;
      const int4 hv = *(const int4*)((char*)hS + idx * 16);
      *(int4*)(P0 + (size_t)(row0 + r) * 1024 + U0g + o * 8) = hv;        // h2b
    }
  }
}

// ---------------------------------------------------------------------------
// Score GEMM: 128x64 tile, 256 thr (4 waves 2Mx2N), 512 blocks (2/CU).
// Double-buffered 2-phase/K-tile, st_16x32 swizzle, counted vmcnt(2).
// ---------------------------------------------------------------------------
__global__ __launch_bounds__(256, 2)
void gemm_score2ph(const unsigned short* A0, int lda0, int K0,
                   const unsigned short* A1, int lda1,
                   const unsigned short* Bw, int K,
                   const float* bias, const unsigned short* X,
                   unsigned short* OutG)
{
  __shared__ unsigned short lds[2][12288];  // [buf][A 128x64 (16KB) | B 64x64 (8KB)]
  const int tid  = threadIdx.x;
  const int wid  = tid >> 6;
  const int lane = tid & 63;
  const int wr = wid >> 1;
  const int wc = wid & 1;
  const int NT = K >> 6;

  const int bid = blockIdx.y * gridDim.x + blockIdx.x;
  const int cpx = (gridDim.x * gridDim.y) >> 3;
  const int swz = (bid & 7) * cpx + (bid >> 3);
  const int row0 = (swz / gridDim.x) * 128;
  const int col0 = (swz % gridDim.x) * 64;

  auto stage_A = [&](int bb, int kt) {
    const int k0 = kt * 64;
    const unsigned short* Ap; int lda, kc;
    if (k0 < K0) { Ap = A0; lda = lda0; kc = k0; }
    else         { Ap = A1; lda = lda1; kc = k0 - K0; }
#pragma unroll
    for (int i = 0; i < 4; ++i) {
      const int x  = (i * 256 + tid) * 16;
      const int xs = x ^ (((x >> 9) & 1) << 5);
      const int r  = xs >> 7;
      const int cb = xs & 127;
      const unsigned short* src = Ap + (size_t)(row0 + r) * lda + kc + (cb >> 1);
      __builtin_amdgcn_global_load_lds((const AS1 void*)src,
          (AS3 void*)((char*)&lds[bb][0] + i * 4096 + wid * 1024), 16, 0, 0);
    }
  };
  auto stage_B = [&](int bb, int kt) {
    const int k0 = kt * 64;
#pragma unroll
    for (int i = 0; i < 2; ++i) {
      const int x  = (i * 256 + tid) * 16;
      const int xs = x ^ (((x >> 9) & 1) << 5);
      const int r  = xs >> 7;
      const int cb = xs & 127;
      const unsigned short* src = Bw + (size_t)(col0 + r) * K + k0 + (cb >> 1);
      __builtin_amdgcn_global_load_lds((const AS1 void*)src,
          (AS3 void*)((char*)&lds[bb][0] + 16384 + i * 4096 + wid * 1024), 16, 0, 0);
    }
  };

  const int frow = lane & 15;
  const int axor = ((lane >> 2) & 1) << 5;
  const int abase = ((((wr * 64 + frow) << 7) + ((lane >> 4) << 4))) ^ axor;
  const int bbase = ((((wc * 32 + frow) << 7) + ((lane >> 4) << 4))) ^ axor;

  const f32x4 zero = {0.f, 0.f, 0.f, 0.f};
  f32x4 acc[4][2];
#pragma unroll
  for (int i = 0; i < 4; ++i)
#pragma unroll
    for (int j = 0; j < 2; ++j) acc[i][j] = zero;

  stage_A(0, 0);
  stage_B(0, 0);
  if (NT > 1) stage_B(1, 1);
  asm volatile("s_waitcnt vmcnt(2)" ::: "memory");
  __builtin_amdgcn_s_barrier();

  for (int kt = 0; kt < NT; ++kt) {
    const int cur = kt & 1;
    const char* ldsA = (const char*)&lds[cur][0];
    const char* ldsB = ldsA + 16384;
    f16x8 bv[2][2];
#pragma unroll
    for (int n = 0; n < 2; ++n) {
      bv[n][0] = *(const f16x8*)(ldsB + bbase + n * 2048);
      bv[n][1] = *(const f16x8*)(ldsB + bbase + n * 2048 + 64);
    }
    f16x8 a00 = *(const f16x8*)(ldsA + abase);
    f16x8 a01 = *(const f16x8*)(ldsA + abase + 64);
    f16x8 a10 = *(const f16x8*)(ldsA + abase + 2048);
    f16x8 a11 = *(const f16x8*)(ldsA + abase + 2048 + 64);
    if (kt + 1 < NT) stage_A(cur ^ 1, kt + 1);
    __builtin_amdgcn_s_barrier();
    asm volatile("s_waitcnt lgkmcnt(0)" ::: "memory");
    __builtin_amdgcn_sched_barrier(0);
    __builtin_amdgcn_s_setprio(1);
#pragma unroll
    for (int n = 0; n < 2; ++n) {
      acc[0][n] = __builtin_amdgcn_mfma_f32_16x16x32_f16(a00, bv[n][0], acc[0][n], 0, 0, 0);
      acc[0][n] = __builtin_amdgcn_mfma_f32_16x16x32_f16(a01, bv[n][1], acc[0][n], 0, 0, 0);
      acc[1][n] = __builtin_amdgcn_mfma_f32_16x16x32_f16(a10, bv[n][0], acc[1][n], 0, 0, 0);
      acc[1][n] = __builtin_amdgcn_mfma_f32_16x16x32_f16(a11, bv[n][1], acc[1][n], 0, 0, 0);
    }
    __builtin_amdgcn_s_setprio(0);
    __builtin_amdgcn_s_barrier();
    f16x8 a20 = *(const f16x8*)(ldsA + abase + 2 * 2048);
    f16x8 a21 = *(const f16x8*)(ldsA + abase + 2 * 2048 + 64);
    f16x8 a30 = *(const f16x8*)(ldsA + abase + 3 * 2048);
    f16x8 a31 = *(const f16x8*)(ldsA + abase + 3 * 2048 + 64);
    if (kt + 2 < NT) stage_B(cur, kt + 2);
    __builtin_amdgcn_s_barrier();
    asm volatile("s_waitcnt lgkmcnt(0)" ::: "memory");
    __builtin_amdgcn_sched_barrier(0);
    __builtin_amdgcn_s_setprio(1);
#pragma unroll
    for (int n = 0; n < 2; ++n) {
      acc[2][n] = __builtin_amdgcn_mfma_f32_16x16x32_f16(a20, bv[n][0], acc[2][n], 0, 0, 0);
      acc[2][n] = __builtin_amdgcn_mfma_f32_16x16x32_f16(a21, bv[n][1], acc[2][n], 0, 0, 0);
      acc[3][n] = __builtin_amdgcn_mfma_f32_16x16x32_f16(a30, bv[n][0], acc[3][n], 0, 0, 0);
      acc[3][n] = __builtin_amdgcn_mfma_f32_16x16x32_f16(a31, bv[n][1], acc[3][n], 0, 0, 0);
    }
    __builtin_amdgcn_s_setprio(0);
    if (kt >= NT - 2) { asm volatile("s_waitcnt vmcnt(0)" ::: "memory"); }
    else              { asm volatile("s_waitcnt vmcnt(2)" ::: "memory"); }
    __builtin_amdgcn_s_barrier();
  }

  const int er = (lane >> 4) << 2;
#pragma unroll
  for (int mi = 0; mi < 4; ++mi)
#pragma unroll
    for (int ni = 0; ni < 2; ++ni) {
      const int row = row0 + wr * 64 + mi * 16 + er;
      const int col = col0 + wc * 32 + ni * 16 + frow;
      const float bs = bias[col];
#pragma unroll
      for (int r = 0; r < 4; ++r) {
        const float v = tanhx(acc[mi][ni][r] + bs);
        const float xv = h2f(X[(size_t)(row + r) * 1024 + col]);
        OutG[(size_t)(row + r) * 2048 + col] = f2h(xv * v);
      }
    }
}

// ---------------------------------------------------------------------------
// Prep kernels
// ---------------------------------------------------------------------------
__global__ void f2h_copy(const float* src, unsigned short* dst, int n) {
  const int i = blockIdx.x * 256 + threadIdx.x;
  if (i < n) dst[i] = f2h(src[i]);
}

__global__ void cat_w_int(const float* wih, const float* whh, unsigned short* dst) {
  const int i = blockIdx.x * 256 + threadIdx.x;   // 4096*2048
  const int n = i >> 11, k = i & 2047;
  const int u = n >> 2, g = n & 3;
  const int src = g * 1024 + u;
  dst[i] = f2h(k < 1024 ? wih[src * 1024 + k] : whh[src * 1024 + (k - 1024)]);
}

__global__ void prep_bias(const float* bih, const float* bhh, float* ib) {
  const int i = blockIdx.x * 256 + threadIdx.x;   // 4096
  const int u = i >> 2, g = i & 3;
  ib[i] = bih[g * 1024 + u] + bhh[g * 1024 + u];
}

__global__ void copy_pq(const float* pq, unsigned short* inb) {
  const int i4 = blockIdx.x * 256 + threadIdx.x;  // float4 index
  const float4 v = ((const float4*)pq)[i4];
  const int base = i4 * 4;
  const float vv[4] = {v.x, v.y, v.z, v.w};
#pragma unroll
  for (int e = 0; e < 4; ++e) {
    const int idx = base + e;
    const int bt = idx / 1003;
    const int j = idx - bt * 1003;
    const int b = bt / 15;
    const int t = bt - b * 15;
    inb[((size_t)t * BATCH + b) * 1024 + j] = f2h(vv[e]);
  }
}

__global__ void cfg_emb(const float* cfg, const int* tim,
                        const float* Wc, const float* bc,
                        const float* eh, const float* ew, const float* es,
                        unsigned short* inb)
{
  const int wv = (blockIdx.x * 256 + threadIdx.x) >> 6;  // row = b*15+t
  const int lane = threadIdx.x & 63;
  const int b = wv / 15, t = wv - b * 15;
  const float* cp = cfg + (size_t)wv * 128;
  const float c0 = cp[lane], c1v = cp[lane + 64];
  unsigned short* dst = inb + ((size_t)t * BATCH + b) * 1024;
#pragma unroll
  for (int g = 0; g < 10; ++g) {
    float v = fmaf(c0, Wc[g * 128 + lane], c1v * Wc[g * 128 + 64 + lane]);
    v += __shfl_xor(v, 32); v += __shfl_xor(v, 16); v += __shfl_xor(v, 8);
    v += __shfl_xor(v, 4);  v += __shfl_xor(v, 2);  v += __shfl_xor(v, 1);
    if (lane == 0) dst[1003 + g] = f2h(v + bc[g]);
  }
  if (lane < 5)       dst[1013 + lane] = f2h(eh[tim[wv * 3 + 0] * 5 + lane]);
  else if (lane < 8)  dst[1018 + (lane - 5)] = f2h(ew[tim[wv * 3 + 1] * 3 + (lane - 5)]);
  else if (lane < 11) dst[1021 + (lane - 8)] = f2h(es[tim[wv * 3 + 2] * 3 + (lane - 8)]);
}

// ---------------------------------------------------------------------------
// BatchNorm over (B,H) per s
// ---------------------------------------------------------------------------
__global__ void bn_partial(const unsigned short* mid, float* part) {
  const int t = blockIdx.y, blk = blockIdx.x, tid = threadIdx.x;
  const unsigned short* p = mid + (size_t)t * BATCH * 1024;
  float s = 0.f, ss = 0.f;
  for (int i = blk * 256 + tid; i < BATCH * 1024; i += 128 * 256) {
    const float v = h2f(p[i]);
    s += v; ss += v * v;
  }
  for (int o = 32; o > 0; o >>= 1) { s += __shfl_down(s, o); ss += __shfl_down(ss, o); }
  __shared__ float sm[8];
  if ((tid & 63) == 0) { sm[(tid >> 6) * 2] = s; sm[(tid >> 6) * 2 + 1] = ss; }
  __syncthreads();
  if (tid == 0) {
    part[(t * 128 + blk) * 2]     = sm[0] + sm[2] + sm[4] + sm[6];
    part[(t * 128 + blk) * 2 + 1] = sm[1] + sm[3] + sm[5] + sm[7];
  }
}

__global__ void bn_final(const float* part, const float* gamma, const float* beta, float* scsh) {
  const int t = blockIdx.x, tid = threadIdx.x;  // 128 threads
  float s = part[(t * 128 + tid) * 2], ss = part[(t * 128 + tid) * 2 + 1];
  for (int o = 32; o > 0; o >>= 1) { s += __shfl_down(s, o); ss += __shfl_down(ss, o); }
  __shared__ float sm[4];
  if ((tid & 63) == 0) { sm[(tid >> 6) * 2] = s; sm[(tid >> 6) * 2 + 1] = ss; }
  __syncthreads();
  if (tid == 0) {
    const float S = sm[0] + sm[2], SS = sm[1] + sm[3];
    const float inv = 1.f / (float)(BATCH * 1024);
    const float mu = S * inv;
    const float var = SS * inv - mu * mu;
    const float rstd = rsqrtf(var + 1e-5f);
    const float sc = rstd * gamma[t];
    scsh[t * 2] = sc;
    scsh[t * 2 + 1] = beta[t] - mu * sc;
  }
}

__global__ void bn_apply(unsigned short* mid, const float* scsh) {
  const int t = blockIdx.y;
  const int i = blockIdx.x * 256 + threadIdx.x;
  unsigned short* p = mid + (size_t)t * BATCH * 1024;
  p[i] = f2h(h2f(p[i]) * scsh[t * 2] + scsh[t * 2 + 1]);
}

// ---------------------------------------------------------------------------
// x-part of attention: xdot[t*B+b] = dot(x_norm[t][b], Wta[2048:3072])
// ---------------------------------------------------------------------------
__global__ void xdot_k(const unsigned short* xn, const float* Wta, float* xdot) {
  const int wv = (blockIdx.x * 256 + threadIdx.x) >> 6;   // row over [0, 15*4096)
  const int lane = threadIdx.x & 63;
  const unsigned short* x = xn + (size_t)wv * 1024;
  const float* wx = Wta + 2048 + lane * 16;
  const f16x8 v0 = ((const f16x8*)x)[lane * 2];
  const f16x8 v1 = ((const f16x8*)x)[lane * 2 + 1];
  float s = 0.f;
#pragma unroll
  for (int e = 0; e < 8; ++e) s = fmaf((float)v0[e], wx[e], s);
#pragma unroll
  for (int e = 0; e < 8; ++e) s = fmaf((float)v1[e], wx[8 + e], s);
  s += __shfl_xor(s, 32); s += __shfl_xor(s, 16); s += __shfl_xor(s, 8);
  s += __shfl_xor(s, 4);  s += __shfl_xor(s, 2);  s += __shfl_xor(s, 1);
  if (lane == 0) xdot[wv] = s;
}

// sum 16 col-block partials -> att2, proj
__global__ void att_reduce(const float* redT, const float* xdot, const float* bta,
                           float* att2, float* proj) {
  const int i = blockIdx.x * 256 + threadIdx.x;   // [0, 15*4096)
  const int t = i >> 12;
  const int b = i & 4095;
  const float* p = redT + (size_t)i * 80;
  float s0 = 0.f, s1 = 0.f, s2 = 0.f, s3 = 0.f, s4 = 0.f;
#pragma unroll
  for (int cb = 0; cb < 16; ++cb) {
    s0 += p[cb * 5 + 0]; s1 += p[cb * 5 + 1]; s2 += p[cb * 5 + 2];
    s3 += p[cb * 5 + 3]; s4 += p[cb * 5 + 4];
  }
  att2[b * SEQ + t] = tanhx(s0 + xdot[i] + bta[0]);
  float* pp = proj + ((size_t)b * SEQ + t) * 4;
  pp[0] = s1; pp[1] = s2; pp[2] = s3; pp[3] = s4;
}

// ---------------------------------------------------------------------------
// Stage 3: chunked pipelined-Jacobi scalar LSTM (exact after 8 iters)
// ---------------------------------------------------------------------------
__global__ __launch_bounds__(256) void lstm3_par(
    const float* proj, const float* Whhd,
    const float* bihd, const float* bhhd, float* out1d)
{
  const int s = blockIdx.x;            // 0..14
  const int tid = threadIdx.x;         // 0..255
  constexpr int CH = BATCH / 256;      // 16
  const float wi = Whhd[0], wf = Whhd[1], wg = Whhd[2], wo = Whhd[3];
  const float bi = bihd[0] + bhhd[0], bf_ = bihd[1] + bhhd[1];
  const float bg = bihd[2] + bhhd[2], bo = bihd[3] + bhhd[3];
  const float4* p4 = (const float4*)proj;
  float4 p[CH];
#pragma unroll
  for (int u = 0; u < CH; ++u) p[u] = p4[(tid * CH + u) * SEQ + s];
  __shared__ float Hb[257], Cb[257];
  Hb[tid] = 0.f; Cb[tid] = 0.f;
  if (tid == 255) { Hb[256] = 0.f; Cb[256] = 0.f; }
  __syncthreads();
  float h, c;
  for (int it = 0; it < 8; ++it) {
    h = Hb[tid]; c = Cb[tid];
#pragma unroll
    for (int u = 0; u < CH; ++u) {
      const float gi = fmaf(h, wi, p[u].x + bi);
      const float gf = fmaf(h, wf, p[u].y + bf_);
      const float gg = fmaf(h, wg, p[u].z + bg);
      const float go = fmaf(h, wo, p[u].w + bo);
      c = sigm(gf) * c + sigm(gi) * tanhx(gg);
      h = sigm(go) * tanhx(c);
    }
    __syncthreads();
    Hb[tid + 1] = h; Cb[tid + 1] = c;
    __syncthreads();
  }
  h = Hb[tid]; c = Cb[tid];
#pragma unroll
  for (int u = 0; u < CH; ++u) {
    const float gi = fmaf(h, wi, p[u].x + bi);
    const float gf = fmaf(h, wf, p[u].y + bf_);
    const float gg = fmaf(h, wg, p[u].z + bg);
    const float go = fmaf(h, wo, p[u].w + bo);
    c = sigm(gf) * c + sigm(gi) * tanhx(gg);
    h = sigm(go) * tanhx(c);
    out1d[(tid * CH + u) * SEQ + s] = h;
  }
}

__global__ void finalize_k(const float* att2, const float* out1d, float* out) {
  const int b = blockIdx.x * 64 + threadIdx.x;
  const float* a = att2 + b * SEQ;
  const float* o = out1d + b * SEQ;
  float m = -1e30f;
  for (int s = 0; s < SEQ; ++s) m = fmaxf(m, a[s]);
  float den = 0.f, num = 0.f;
  for (int s = 0; s < SEQ; ++s) {
    const float e = __expf(a[s] - m);
    den += e; num += e * o[s];
  }
  out[b] = num / den;
}

// ---------------------------------------------------------------------------
extern "C" void kernel_launch(void* const* d_in, const int* in_sizes, int n_in,
                              void* d_out, int out_size, void* d_ws, size_t ws_size,
                              hipStream_t stream)
{
  (void)in_sizes; (void)n_in; (void)out_size; (void)ws_size;
  const float* in_pq   = (const float*)d_in[0];
  const float* in_cfg  = (const float*)d_in[1];
  const int*   in_time = (const int*)d_in[2];
  const float* W_cfg   = (const float*)d_in[3];
  const float* b_cfg   = (const float*)d_in[4];
  const float* emb_h   = (const float*)d_in[5];
  const float* emb_w   = (const float*)d_in[6];
  const float* emb_s   = (const float*)d_in[7];
  const float* W_sa    = (const float*)d_in[8];
  const float* b_sa    = (const float*)d_in[9];
  const float* Wih_s   = (const float*)d_in[10];
  const float* Whh_s   = (const float*)d_in[11];
  const float* bih_s   = (const float*)d_in[12];
  const float* bhh_s   = (const float*)d_in[13];
  const float* Wih_t   = (const float*)d_in[14];
  const float* Whh_t   = (const float*)d_in[15];
  const float* bih_t   = (const float*)d_in[16];
  const float* bhh_t   = (const float*)d_in[17];
  const float* W_ta    = (const float*)d_in[18];
  const float* b_ta    = (const float*)d_in[19];
  const float* gamma   = (const float*)d_in[20];
  const float* beta    = (const float*)d_in[21];
  const float* Wih_d   = (const float*)d_in[22];
  const float* Whh_d   = (const float*)d_in[23];
  const float* bih_d   = (const float*)d_in[24];
  const float* bhh_d   = (const float*)d_in[25];
  float* out = (float*)d_out;

  char* w = (char*)d_ws;
  size_t off = 0;
  auto alloc = [&](size_t bytes) -> char* {
    char* p = w + off;
    off = (off + bytes + 255) & ~(size_t)255;
    return p;
  };
  unsigned short* inb  = (unsigned short*)alloc((size_t)SEQ * BATCH * 1024 * 2);
  unsigned short* hc   = (unsigned short*)alloc((size_t)BATCH * 2048 * 2);
  unsigned short* gA0  = (unsigned short*)alloc((size_t)BATCH * 2048 * 2);
  unsigned short* gA1  = (unsigned short*)alloc((size_t)BATCH * 2048 * 2);
  float*          c1   = (float*)alloc((size_t)BATCH * 1024 * 4);
  unsigned short* h2b0 = (unsigned short*)alloc((size_t)BATCH * 1024 * 2);
  unsigned short* h2b1 = (unsigned short*)alloc((size_t)BATCH * 1024 * 2);
  float*          c2f  = (float*)alloc((size_t)BATCH * 1024 * 4);
  unsigned short* wsab = (unsigned short*)alloc((size_t)1024 * 3072 * 2);
  unsigned short* w1   = (unsigned short*)alloc((size_t)4096 * 2048 * 2);
  unsigned short* w2   = (unsigned short*)alloc((size_t)4096 * 2048 * 2);
  float*          ib1  = (float*)alloc(4096 * 4);
  float*          ib2  = (float*)alloc(4096 * 4);
  float*          part = (float*)alloc(15 * 128 * 2 * 4);
  float*          scsh = (float*)alloc(15 * 2 * 4);
  float*          att2 = (float*)alloc((size_t)BATCH * SEQ * 4);
  float*          proj = (float*)alloc((size_t)BATCH * SEQ * 4 * 4);
  float*          o1d  = (float*)alloc((size_t)BATCH * SEQ * 4);
  float*          redT = (float*)alloc((size_t)SEQ * BATCH * 16 * 5 * 4);
  float*          xdot = (float*)alloc((size_t)SEQ * BATCH * 4);

  unsigned short* gAbuf[2]  = {gA0, gA1};
  unsigned short* h2bbuf[2] = {h2b0, h2b1};

  // zero recurrent state each call (deterministic)
  hipMemsetAsync(hc,   0, (size_t)BATCH * 2048 * 2, stream);
  hipMemsetAsync(gA0,  0, (size_t)BATCH * 2048 * 2, stream);
  hipMemsetAsync(c1,   0, (size_t)BATCH * 1024 * 4, stream);
  hipMemsetAsync(h2b0, 0, (size_t)BATCH * 1024 * 2, stream);
  hipMemsetAsync(c2f,  0, (size_t)BATCH * 1024 * 4, stream);

  // weight conversion + input assembly
  f2h_copy<<<(1024 * 3072) / 256, 256, 0, stream>>>(W_sa, wsab, 1024 * 3072);
  cat_w_int<<<(4096 * 2048) / 256, 256, 0, stream>>>(Wih_s, Whh_s, w1);
  cat_w_int<<<(4096 * 2048) / 256, 256, 0, stream>>>(Wih_t, Whh_t, w2);
  prep_bias<<<16, 256, 0, stream>>>(bih_s, bhh_s, ib1);
  prep_bias<<<16, 256, 0, stream>>>(bih_t, bhh_t, ib2);
  copy_pq<<<(BATCH * SEQ * 1003 / 4) / 256, 256, 0, stream>>>(in_pq, inb);
  cfg_emb<<<(BATCH * SEQ) / 4, 256, 0, stream>>>(in_cfg, in_time, W_cfg, b_cfg,
                                                 emb_h, emb_w, emb_s, inb);

  // ---- stage 1 ----
  for (int t = 0; t < SEQ; ++t) {
    unsigned short* xt = inb + (size_t)t * BATCH * 1024;
    gemm_score2ph<<<dim3(1024 / 64, BATCH / 128), 256, 0, stream>>>(
        hc, 2048, 2048, xt, 1024, wsab, 3072, b_sa, xt, gAbuf[t & 1]);
    gemm_lstm256<1><<<dim3(4096 / 256, BATCH / 256), 512, 0, stream>>>(
        gAbuf[t & 1], 2048, 2048, gAbuf[t & 1], 2048, w1, 2048,
        ib1, c1, hc, gAbuf[(t + 1) & 1], xt, nullptr, nullptr, nullptr);
  }

  // ---- batchnorm over (B,H) per s ----
  bn_partial<<<dim3(128, SEQ), 256, 0, stream>>>(inb, part);
  bn_final<<<SEQ, 128, 0, stream>>>(part, gamma, beta, scsh);
  bn_apply<<<dim3((BATCH * 1024) / 256, SEQ), 256, 0, stream>>>(inb, scsh);
  xdot_k<<<(SEQ * BATCH * 64) / 256, 256, 0, stream>>>(inb, W_ta, xdot);

  // ---- stage 2 (fused LSTM + attention partials) ----
  for (int t = 0; t < SEQ; ++t) {
    const unsigned short* xt = inb + (size_t)t * BATCH * 1024;
    gemm_lstm256<2><<<dim3(4096 / 256, BATCH / 256), 512, 0, stream>>>(
        xt, 1024, 1024, h2bbuf[t & 1], 1024, w2, 2048,
        ib2, c2f, h2bbuf[(t + 1) & 1], nullptr, nullptr,
        W_ta, Wih_d, redT + (size_t)t * BATCH * 80);
  }
  att_reduce<<<(SEQ * BATCH) / 256, 256, 0, stream>>>(redT, xdot, b_ta, att2, proj);

  // ---- stage 3 + output ----
  lstm3_par<<<SEQ, 256, 0, stream>>>(proj, Whh_d, bih_d, bhh_d, o1d);
  finalize_k<<<BATCH / 64, 64, 0, stream>>>(att2, o1d, out);
}